// Round 12
// baseline (443.325 us; speedup 1.0000x reference)
//
#include <hip/hip_runtime.h>
#include <math.h>

#define NN 100000
#define NE 3200000
#define NBUCK 782   // buckets of 128 cols
#define EPB 4096    // edges per partition block
#define NBLK 782    // ceil(NE/EPB)
#define SB_Q 16     // buckets per k_scanb block
#define SCAP 4608   // k_build LDS stage capacity (mean 4092, +8 sigma)
#define BN_EPS 1e-5f

static inline size_t alignup(size_t v) { return (v + 255) & ~size_t(255); }

__device__ inline unsigned short f2bf(float x) {  // round-to-nearest bf16
  unsigned u = __float_as_uint(x);
  u += 0x7FFF + ((u >> 16) & 1);
  return (unsigned short)(u >> 16);
}
__device__ inline float bf2f(unsigned short h) {
  return __uint_as_float((unsigned)h << 16);
}
// edge entry: bits[16:0]=row, bits[31:17]=top 15 bits of fp32 weight (RN)
__device__ inline float edgew(int e) {
  return __uint_as_float((unsigned)e & 0xFFFE0000u);
}

// ---------- A: per-block bucket histogram ----------
__global__ void k_hist(const int* __restrict__ col, int* __restrict__ cntm) {
  __shared__ int cnt[NBUCK];
  for (int i = threadIdx.x; i < NBUCK; i += 256) cnt[i] = 0;
  __syncthreads();
  int e0 = blockIdx.x * EPB;
  int nE = min(EPB, NE - e0);
  for (int i = threadIdx.x; i < nE; i += 256) atomicAdd(&cnt[col[e0 + i] >> 7], 1);
  __syncthreads();
  int* dst = cntm + (size_t)blockIdx.x * NBUCK;
  for (int i = threadIdx.x; i < NBUCK; i += 256) dst[i] = cnt[i];
}

// ---------- B: per-bucket exclusive scan over blocks (+ total row NBLK) ----------
__global__ void k_scanb(const int* __restrict__ cntm, int* __restrict__ basem,
                        int* __restrict__ btot) {
  __shared__ int s[NBLK][SB_Q + 1];
  int q0 = blockIdx.x * SB_Q;
  int nq = min(SB_Q, NBUCK - q0);
  int t = threadIdx.x;
  for (int idx = t; idx < NBLK * SB_Q; idx += 256) {
    int i = idx >> 4, j = idx & 15;
    s[i][j] = (j < nq) ? cntm[(size_t)i * NBUCK + q0 + j] : 0;
  }
  __syncthreads();
  int wave = t >> 6, lane = t & 63;
  for (int j = wave; j < SB_Q; j += 4) {
    int carry = 0;
    for (int c = 0; c < (NBLK + 63) / 64; ++c) {
      int i = c * 64 + lane;
      int v = (i < NBLK) ? s[i][j] : 0;
      int x = v;
      #pragma unroll
      for (int d = 1; d < 64; d <<= 1) {
        int tt = __shfl_up(x, d, 64);
        if (lane >= d) x += tt;
      }
      if (i < NBLK) s[i][j] = x - v + carry;
      carry += __shfl(x, 63, 64);
    }
    if (lane == 0 && j < nq) {
      btot[q0 + j] = carry;
      basem[(size_t)NBLK * NBUCK + q0 + j] = carry;  // total row
    }
  }
  __syncthreads();
  for (int idx = t; idx < NBLK * SB_Q; idx += 256) {
    int i = idx >> 4, j = idx & 15;
    if (j < nq) basem[(size_t)i * NBUCK + q0 + j] = s[i][j];
  }
}

// ---------- C: exclusive scan of bucket totals ----------
__global__ void k_scanq(const int* __restrict__ btot, int* __restrict__ gbase) {
  __shared__ int s[NBUCK];
  __shared__ int c[256];
  const int NCH = (NBUCK + 3) / 4;
  int t = threadIdx.x;
  for (int i = t; i < NBUCK; i += 256) s[i] = btot[i];
  __syncthreads();
  if (t < NCH) {
    int b0 = 4 * t, sum = 0;
    #pragma unroll
    for (int j = 0; j < 4; ++j) if (b0 + j < NBUCK) sum += s[b0 + j];
    c[t] = sum;
  }
  __syncthreads();
  for (int d = 1; d < NCH; d <<= 1) {
    int v = (t < NCH && t >= d) ? c[t - d] : 0;
    __syncthreads();
    if (t < NCH) c[t] += v;
    __syncthreads();
  }
  if (t < NCH) {
    int b0 = 4 * t;
    int run = (t > 0) ? c[t - 1] : 0;
    #pragma unroll
    for (int j = 0; j < 4; ++j)
      if (b0 + j < NBUCK) { int v = s[b0 + j]; s[b0 + j] = run; run += v; }
  }
  __syncthreads();
  for (int i = t; i < NBUCK; i += 256) gbase[i] = s[i];
}

// ---------- D: scatter via LDS sort-stage (counts from basem diff) ----------
__global__ void k_scat(const int* __restrict__ row, const int* __restrict__ col,
                       const float* __restrict__ ew, const int* __restrict__ basem,
                       const int* __restrict__ gbase, int2* __restrict__ bin) {
  __shared__ int segB[NBUCK];
  __shared__ int cnt[NBUCK];
  __shared__ int csc[256];
  __shared__ int2 stage[EPB];
  __shared__ unsigned short qarr[EPB];
  int b = blockIdx.x, t = threadIdx.x;
  const int* rowA = basem + (size_t)b * NBUCK;
  const int* rowB = basem + (size_t)(b + 1) * NBUCK;
  for (int i = t; i < NBUCK; i += 256) {
    int a = rowA[i];
    segB[i] = gbase[i] + a;
    cnt[i] = rowB[i] - a;
  }
  __syncthreads();
  const int NCH = (NBUCK + 3) / 4;
  int q4 = 4 * t;
  if (t < NCH) {
    int sum = 0;
    #pragma unroll
    for (int j = 0; j < 4; ++j) if (q4 + j < NBUCK) sum += cnt[q4 + j];
    csc[t] = sum;
  }
  __syncthreads();
  for (int d = 1; d < NCH; d <<= 1) {
    int v = (t < NCH && t >= d) ? csc[t - d] : 0;
    __syncthreads();
    if (t < NCH) csc[t] += v;
    __syncthreads();
  }
  if (t < NCH) {
    int run = (t > 0) ? csc[t - 1] : 0;
    #pragma unroll
    for (int j = 0; j < 4; ++j)
      if (q4 + j < NBUCK) {
        int v = cnt[q4 + j];
        segB[q4 + j] -= run;
        cnt[q4 + j] = run;
        run += v;
      }
  }
  __syncthreads();
  int e0 = b * EPB;
  int nE = min(EPB, NE - e0);
  for (int i = t; i < nE; i += 256) {
    int e = e0 + i;
    int cc = col[e], q = cc >> 7;
    int p = atomicAdd(&cnt[q], 1);
    stage[p] = make_int2(row[e] | ((cc & 127) << 17), __float_as_int(ew[e]));
    qarr[p] = (unsigned short)q;
  }
  __syncthreads();
  for (int p = t; p < nE; p += 256) {
    int q = qarr[p];
    bin[segB[q] + p] = stage[p];
  }
}

// ---------- E: counting sort + bucket-local degree-sorted perm ----------
__global__ void k_build(const int* __restrict__ gbase, const int* __restrict__ btot,
                        const int2* __restrict__ bin,
                        int* __restrict__ csr, float* __restrict__ dis,
                        int* __restrict__ nstart, int* __restrict__ ncnt,
                        int* __restrict__ perm) {
  __shared__ int2 stage[SCAP];
  __shared__ int cnt[128];
  __shared__ float degw[128];
  __shared__ int off[129];
  __shared__ int dh[129];
  int b = blockIdx.x;
  int gb0 = gbase[b];
  int nb = btot[b];
  const int2* gb = bin + gb0;
  for (int i = threadIdx.x; i < 128; i += 256) { cnt[i] = 0; degw[i] = 0.f; }
  for (int i = threadIdx.x; i < 129; i += 256) dh[i] = 0;
  __syncthreads();
  for (int i = threadIdx.x; i < nb; i += 256) {
    int2 v = gb[i];
    if (i < SCAP) stage[i] = v;
    int c = (v.x >> 17) & 127;
    atomicAdd(&cnt[c], 1);
    atomicAdd(&degw[c], __int_as_float(v.y));
  }
  __syncthreads();
  if (threadIdx.x == 0) {
    int s = 0;
    for (int c = 0; c < 128; ++c) { off[c] = s; s += cnt[c]; }
    off[128] = s;
  }
  __syncthreads();
  for (int c = threadIdx.x; c < 128; c += 256) {
    int n = b * 128 + c;
    if (n < NN) {
      nstart[n] = gb0 + off[c];
      ncnt[n] = cnt[c];
      float d = degw[c];
      dis[n] = (d > 0.f) ? rsqrtf(fmaxf(d, 1e-12f)) : 0.f;
      atomicAdd(&dh[min(cnt[c], 127) + 1], 1);  // degree histogram (shifted)
    }
  }
  __syncthreads();
  if (threadIdx.x == 0) {
    for (int d = 1; d < 129; ++d) dh[d] += dh[d - 1];  // dh[d] = start of degree d
  }
  __syncthreads();
  for (int c = threadIdx.x; c < 128; c += 256) {
    int n = b * 128 + c;
    if (n < NN) {
      int r = atomicAdd(&dh[min(cnt[c], 127)], 1);  // rank within bucket, asc degree
      perm[b * 128 + r] = n;
    }
  }
  __syncthreads();
  for (int i = threadIdx.x; i < 128; i += 256) cnt[i] = 0;
  __syncthreads();
  int* cb = csr + gb0;
  for (int i = threadIdx.x; i < nb; i += 256) {
    int2 v = (i < SCAP) ? stage[i] : gb[i];
    int c = (v.x >> 17) & 127;
    int pos = off[c] + atomicAdd(&cnt[c], 1);
    unsigned u = (unsigned)v.y;
    u += 0xFFFFu + ((u >> 17) & 1);  // RN to 15-bit weight
    cb[pos] = (v.x & 0x1FFFF) | (int)(u & 0xFFFE0000u);
  }
}

// ---------- conv1 ----------
__global__ void k_init1(const float* __restrict__ x, const float* __restrict__ rw,
                        const float* __restrict__ bias, const float* __restrict__ dis,
                        unsigned short* __restrict__ root1, float* __restrict__ s) {
  int idx = blockIdx.x * 256 + threadIdx.x;  // n*16 + f
  if (idx >= NN * 16) return;
  int n = idx >> 4, f = idx & 15;
  float xv = x[n];
  if (f == 0) s[n] = dis[n] * xv;
  root1[n * 48 + f]      = f2bf(xv * rw[f]      + bias[f]);
  root1[n * 48 + 16 + f] = f2bf(xv * rw[16 + f] + bias[16 + f]);
  root1[n * 48 + 32 + f] = f2bf(xv * rw[32 + f] + bias[32 + f]);
}

// Pass 1 exploits rank-1 input: gather is a SCALAR sum g = sum_e w_e*dis_r*x_r.
__global__ void k_prop_first(const float* __restrict__ s,
                             const unsigned short* __restrict__ root,
                             ushort4* __restrict__ outp, const int* __restrict__ csr,
                             const int* __restrict__ nstart, const int* __restrict__ ncnt,
                             const float* __restrict__ dis, const float* __restrict__ w,
                             const float* __restrict__ iw, const int* __restrict__ perm) {
  __shared__ float ws[768];
  for (int i = threadIdx.x; i < 768; i += 256) ws[i] = w[i];
  __syncthreads();
  int f = threadIdx.x & 15;
  int gid = (blockIdx.x * 256 + threadIdx.x) >> 4;
  if (gid >= NN) return;
  int n = perm[gid];
  int e0 = nstart[n], cnt = ncnt[n];
  float g = 0.f;
  for (int i = f; i < cnt; i += 16) {
    int e = csr[e0 + i];
    g = fmaf(edgew(e), s[e & 0x1FFFF], g);
  }
  #pragma unroll
  for (int d = 8; d; d >>= 1) g += __shfl_xor(g, d, 16);
  float dn = dis[n];
  float dg = dn * g;
  float a0 = fmaxf(fmaf(dg, iw[f],      bf2f(root[n * 48 + f])),      0.f);
  float a1 = fmaxf(fmaf(dg, iw[16 + f], bf2f(root[n * 48 + 16 + f])), 0.f);
  float a2 = fmaxf(fmaf(dg, iw[32 + f], bf2f(root[n * 48 + 32 + f])), 0.f);
  float n0 = 0.f, n1 = 0.f, n2 = 0.f;
  #pragma unroll
  for (int f2 = 0; f2 < 16; ++f2) {
    float b0 = __shfl(a0, f2, 16);
    float b1 = __shfl(a1, f2, 16);
    float b2v = __shfl(a2, f2, 16);
    n0 = fmaf(b0, ws[f2 * 16 + f], n0);
    n1 = fmaf(b1, ws[256 + f2 * 16 + f], n1);
    n2 = fmaf(b2v, ws[512 + f2 * 16 + f], n2);
  }
  ushort4 pk;
  pk.x = f2bf(dn * n0); pk.y = f2bf(dn * n1); pk.z = f2bf(dn * n2); pk.w = 0;
  outp[(size_t)n * 16 + f] = pk;
}

// 16 lanes per dest node (degree-sorted via perm for wave balance).
template <bool APPLY_W>
__global__ void k_prop16(const ushort4* __restrict__ in,
                         const unsigned short* __restrict__ root,
                         ushort4* __restrict__ outp, const int* __restrict__ csr,
                         const int* __restrict__ nstart, const int* __restrict__ ncnt,
                         const float* __restrict__ dis, const float* __restrict__ w,
                         const float* __restrict__ bng, const float* __restrict__ bnb,
                         const float* __restrict__ bnm, const float* __restrict__ bnv,
                         const float* __restrict__ iw2, const float* __restrict__ rw2,
                         const float* __restrict__ b2,
                         float4* __restrict__ root2, ushort4* __restrict__ o2,
                         const int* __restrict__ perm) {
  __shared__ float ws[768];
  if (APPLY_W) {
    for (int i = threadIdx.x; i < 768; i += 256) ws[i] = w[i];
    __syncthreads();
  }
  int f = threadIdx.x & 15;
  int gid = (blockIdx.x * 256 + threadIdx.x) >> 4;
  if (gid >= NN) return;
  int n = perm[gid];
  int e0 = nstart[n], cnt = ncnt[n];
  float a0 = 0.f, a1 = 0.f, a2 = 0.f;
  int i = 0;
  for (; i + 8 <= cnt; i += 8) {
    int e[8];
    ushort4 v[8];
    #pragma unroll
    for (int j = 0; j < 8; ++j) e[j] = csr[e0 + i + j];
    #pragma unroll
    for (int j = 0; j < 8; ++j) v[j] = in[(size_t)(e[j] & 0x1FFFF) * 16 + f];
    #pragma unroll
    for (int j = 0; j < 8; ++j) {
      float we = edgew(e[j]);
      a0 = fmaf(we, bf2f(v[j].x), a0);
      a1 = fmaf(we, bf2f(v[j].y), a1);
      a2 = fmaf(we, bf2f(v[j].z), a2);
    }
  }
  for (; i + 4 <= cnt; i += 4) {
    int e[4];
    ushort4 v[4];
    #pragma unroll
    for (int j = 0; j < 4; ++j) e[j] = csr[e0 + i + j];
    #pragma unroll
    for (int j = 0; j < 4; ++j) v[j] = in[(size_t)(e[j] & 0x1FFFF) * 16 + f];
    #pragma unroll
    for (int j = 0; j < 4; ++j) {
      float we = edgew(e[j]);
      a0 = fmaf(we, bf2f(v[j].x), a0);
      a1 = fmaf(we, bf2f(v[j].y), a1);
      a2 = fmaf(we, bf2f(v[j].z), a2);
    }
  }
  for (; i < cnt; ++i) {
    int e = csr[e0 + i];
    float we = edgew(e);
    ushort4 v = in[(size_t)(e & 0x1FFFF) * 16 + f];
    a0 = fmaf(we, bf2f(v.x), a0);
    a1 = fmaf(we, bf2f(v.y), a1);
    a2 = fmaf(we, bf2f(v.z), a2);
  }
  float dn = dis[n];
  a0 = fmaxf(fmaf(dn, a0, bf2f(root[n * 48 + f])),      0.f);
  a1 = fmaxf(fmaf(dn, a1, bf2f(root[n * 48 + 16 + f])), 0.f);
  a2 = fmaxf(fmaf(dn, a2, bf2f(root[n * 48 + 32 + f])), 0.f);
  if (APPLY_W) {
    float n0 = 0.f, n1 = 0.f, n2 = 0.f;
    #pragma unroll
    for (int f2 = 0; f2 < 16; ++f2) {
      float b0 = __shfl(a0, f2, 16);
      float b1 = __shfl(a1, f2, 16);
      float b2v = __shfl(a2, f2, 16);
      n0 = fmaf(b0, ws[f2 * 16 + f], n0);
      n1 = fmaf(b1, ws[256 + f2 * 16 + f], n1);
      n2 = fmaf(b2v, ws[512 + f2 * 16 + f], n2);
    }
    ushort4 pk;
    pk.x = f2bf(dn * n0); pk.y = f2bf(dn * n1); pk.z = f2bf(dn * n2); pk.w = 0;
    outp[(size_t)n * 16 + f] = pk;
  } else {
    float mean = (a0 + a1 + a2) * (1.f / 3.f);
    float hv = fmaxf((mean - bnm[f]) * rsqrtf(bnv[f] + BN_EPS) * bng[f] + bnb[f], 0.f);
    float d0 = hv * iw2[f],      r0 = hv * rw2[f];
    float d1 = hv * iw2[16 + f], r1 = hv * rw2[16 + f];
    float d2 = hv * iw2[32 + f], r2 = hv * rw2[32 + f];
    #pragma unroll
    for (int d = 8; d; d >>= 1) {
      d0 += __shfl_xor(d0, d, 16); r0 += __shfl_xor(r0, d, 16);
      d1 += __shfl_xor(d1, d, 16); r1 += __shfl_xor(r1, d, 16);
      d2 += __shfl_xor(d2, d, 16); r2 += __shfl_xor(r2, d, 16);
    }
    if (f == 0) {
      float4 rt;
      rt.x = r0 + b2[0]; rt.y = r1 + b2[1]; rt.z = r2 + b2[2]; rt.w = 0.f;
      root2[n] = rt;
      ushort4 pk;
      pk.x = f2bf(dn * d0); pk.y = f2bf(dn * d1); pk.z = f2bf(dn * d2); pk.w = 0;
      o2[n] = pk;
    }
  }
}

// ---------- conv2: 16 lanes split edges; state bf16 ushort4 ----------
template <bool LAST>
__global__ void k_prop1(const ushort4* __restrict__ in, const float4* __restrict__ root,
                        ushort4* __restrict__ outp, float* __restrict__ outf,
                        const int* __restrict__ csr,
                        const int* __restrict__ nstart, const int* __restrict__ ncnt,
                        const float* __restrict__ dis, const float* __restrict__ w2,
                        const int* __restrict__ perm) {
  int lane = threadIdx.x & 15;
  int gid = (blockIdx.x * 256 + threadIdx.x) >> 4;
  if (gid >= NN) return;
  int n = perm[gid];
  int e0 = nstart[n], cnt = ncnt[n];
  float a0 = 0.f, a1 = 0.f, a2 = 0.f;
  for (int i = lane; i < cnt; i += 16) {
    int e = csr[e0 + i];
    float we = edgew(e);
    ushort4 src = in[e & 0x1FFFF];
    a0 = fmaf(we, bf2f(src.x), a0);
    a1 = fmaf(we, bf2f(src.y), a1);
    a2 = fmaf(we, bf2f(src.z), a2);
  }
  #pragma unroll
  for (int d = 8; d; d >>= 1) {
    a0 += __shfl_xor(a0, d, 16);
    a1 += __shfl_xor(a1, d, 16);
    a2 += __shfl_xor(a2, d, 16);
  }
  if (lane == 0) {
    float dn = dis[n];
    float4 rt = root[n];
    if (LAST) {
      float s = fmaf(dn, a0, rt.x) + fmaf(dn, a1, rt.y) + fmaf(dn, a2, rt.z);
      s *= (1.f / 3.f);
      outf[n] = 1.f / (1.f + expf(-s));
    } else {
      ushort4 pk;
      pk.x = f2bf(dn * fmaf(dn, a0, rt.x) * w2[0]);
      pk.y = f2bf(dn * fmaf(dn, a1, rt.y) * w2[1]);
      pk.z = f2bf(dn * fmaf(dn, a2, rt.z) * w2[2]);
      pk.w = 0;
      outp[n] = pk;
    }
  }
}

// ---------- launch ----------
extern "C" void kernel_launch(void* const* d_in, const int* in_sizes, int n_in,
                              void* d_out, int out_size, void* d_ws, size_t ws_size,
                              hipStream_t stream) {
  const float* x     = (const float*)d_in[0];
  const int*   ei    = (const int*)d_in[1];
  const float* ew    = (const float*)d_in[2];
  const float* c1_iw = (const float*)d_in[3];
  const float* c1_w  = (const float*)d_in[4];
  const float* c1_rw = (const float*)d_in[5];
  const float* c1_b  = (const float*)d_in[6];
  const float* bn_g  = (const float*)d_in[7];
  const float* bn_b  = (const float*)d_in[8];
  const float* bn_m  = (const float*)d_in[9];
  const float* bn_v  = (const float*)d_in[10];
  const float* c2_iw = (const float*)d_in[11];
  const float* c2_w  = (const float*)d_in[12];
  const float* c2_rw = (const float*)d_in[13];
  const float* c2_b  = (const float*)d_in[14];
  float* out = (float*)d_out;

  char* p = (char*)d_ws;
  auto take = [&](size_t bytes) -> char* { char* r = p; p += alignup(bytes); return r; };
  int*     cntm   = (int*)take((size_t)NBLK * NBUCK * 4);
  int*     basem  = (int*)take((size_t)(NBLK + 1) * NBUCK * 4);
  int*     btot   = (int*)take((size_t)NBUCK * 4);
  int*     gbase  = (int*)take((size_t)NBUCK * 4);
  int2*    bin    = (int2*)take((size_t)NE * 8);
  int*     csr    = (int*)take((size_t)NE * 4);
  float*   dis    = (float*)take((size_t)NN * 4);
  int*     nst    = (int*)take((size_t)NN * 4);
  int*     ncn    = (int*)take((size_t)NN * 4);
  int*     perm   = (int*)take((size_t)NN * 4);
  unsigned short* root1 = (unsigned short*)take((size_t)NN * 48 * 2);
  float*   sbuf   = (float*)take((size_t)NN * 4);
  ushort4* bufA   = (ushort4*)take((size_t)NN * 16 * 8);
  ushort4* bufB   = (ushort4*)take((size_t)NN * 16 * 8);
  float4*  root2  = (float4*)take((size_t)NN * 16);
  ushort4* o2A    = (ushort4*)take((size_t)NN * 8);
  ushort4* o2B    = (ushort4*)take((size_t)NN * 8);

  const int* row = ei;
  const int* col = ei + NE;

  const int gP = (NN * 16 + 255) / 256;
  const int gSB = (NBUCK + SB_Q - 1) / SB_Q;

  k_hist <<<NBLK, 256, 0, stream>>>(col, cntm);
  k_scanb<<<gSB, 256, 0, stream>>>(cntm, basem, btot);
  k_scanq<<<1, 256, 0, stream>>>(btot, gbase);
  k_scat <<<NBLK, 256, 0, stream>>>(row, col, ew, basem, gbase, bin);
  k_build<<<NBUCK, 256, 0, stream>>>(gbase, btot, bin, csr, dis, nst, ncn, perm);

  k_init1<<<gP, 256, 0, stream>>>(x, c1_rw, c1_b, dis, root1, sbuf);
  k_prop_first<<<gP, 256, 0, stream>>>(sbuf, root1, bufA, csr, nst, ncn, dis, c1_w, c1_iw, perm);
  k_prop16<true ><<<gP, 256, 0, stream>>>(bufA, root1, bufB, csr, nst, ncn, dis, c1_w,
      nullptr, nullptr, nullptr, nullptr, nullptr, nullptr, nullptr, nullptr, nullptr, perm);
  k_prop16<true ><<<gP, 256, 0, stream>>>(bufB, root1, bufA, csr, nst, ncn, dis, c1_w,
      nullptr, nullptr, nullptr, nullptr, nullptr, nullptr, nullptr, nullptr, nullptr, perm);
  k_prop16<false><<<gP, 256, 0, stream>>>(bufA, root1, nullptr, csr, nst, ncn, dis, nullptr,
      bn_g, bn_b, bn_m, bn_v, c2_iw, c2_rw, c2_b, root2, o2A, perm);

  k_prop1<false><<<gP, 256, 0, stream>>>(o2A, root2, o2B, nullptr, csr, nst, ncn, dis, c2_w, perm);
  k_prop1<false><<<gP, 256, 0, stream>>>(o2B, root2, o2A, nullptr, csr, nst, ncn, dis, c2_w, perm);
  k_prop1<false><<<gP, 256, 0, stream>>>(o2A, root2, o2B, nullptr, csr, nst, ncn, dis, c2_w, perm);
  k_prop1<true ><<<gP, 256, 0, stream>>>(o2B, root2, nullptr, out, csr, nst, ncn, dis, c2_w, perm);
}

// Round 13
// 442.250 us; speedup vs baseline: 1.0024x; 1.0024x over previous
//
#include <hip/hip_runtime.h>
#include <math.h>

#define NN 100000
#define NE 3200000
#define NBUCK 782   // buckets of 128 cols
#define EPB 4096    // edges per partition block
#define NBLK 782    // ceil(NE/EPB)
#define SB_Q 16     // buckets per k_scanb block
#define SCAP 4608   // k_build LDS stage capacity (mean 4092, +8 sigma)
#define BN_EPS 1e-5f

static inline size_t alignup(size_t v) { return (v + 255) & ~size_t(255); }

__device__ inline unsigned short f2bf(float x) {  // round-to-nearest bf16
  unsigned u = __float_as_uint(x);
  u += 0x7FFF + ((u >> 16) & 1);
  return (unsigned short)(u >> 16);
}
__device__ inline float bf2f(unsigned short h) {
  return __uint_as_float((unsigned)h << 16);
}
// edge entry: bits[16:0]=row(new id), bits[31:17]=top 15 bits of fp32 weight (RN)
__device__ inline float edgew(int e) {
  return __uint_as_float((unsigned)e & 0xFFFE0000u);
}

// ---------- A: per-block bucket histogram ----------
__global__ void k_hist(const int* __restrict__ col, int* __restrict__ cntm) {
  __shared__ int cnt[NBUCK];
  for (int i = threadIdx.x; i < NBUCK; i += 256) cnt[i] = 0;
  __syncthreads();
  int e0 = blockIdx.x * EPB;
  int nE = min(EPB, NE - e0);
  for (int i = threadIdx.x; i < nE; i += 256) atomicAdd(&cnt[col[e0 + i] >> 7], 1);
  __syncthreads();
  int* dst = cntm + (size_t)blockIdx.x * NBUCK;
  for (int i = threadIdx.x; i < NBUCK; i += 256) dst[i] = cnt[i];
}

// ---------- B: per-bucket exclusive scan over blocks (+ total row NBLK) ----------
__global__ void k_scanb(const int* __restrict__ cntm, int* __restrict__ basem,
                        int* __restrict__ btot) {
  __shared__ int s[NBLK][SB_Q + 1];
  int q0 = blockIdx.x * SB_Q;
  int nq = min(SB_Q, NBUCK - q0);
  int t = threadIdx.x;
  for (int idx = t; idx < NBLK * SB_Q; idx += 256) {
    int i = idx >> 4, j = idx & 15;
    s[i][j] = (j < nq) ? cntm[(size_t)i * NBUCK + q0 + j] : 0;
  }
  __syncthreads();
  int wave = t >> 6, lane = t & 63;
  for (int j = wave; j < SB_Q; j += 4) {
    int carry = 0;
    for (int c = 0; c < (NBLK + 63) / 64; ++c) {
      int i = c * 64 + lane;
      int v = (i < NBLK) ? s[i][j] : 0;
      int x = v;
      #pragma unroll
      for (int d = 1; d < 64; d <<= 1) {
        int tt = __shfl_up(x, d, 64);
        if (lane >= d) x += tt;
      }
      if (i < NBLK) s[i][j] = x - v + carry;
      carry += __shfl(x, 63, 64);
    }
    if (lane == 0 && j < nq) {
      btot[q0 + j] = carry;
      basem[(size_t)NBLK * NBUCK + q0 + j] = carry;  // total row
    }
  }
  __syncthreads();
  for (int idx = t; idx < NBLK * SB_Q; idx += 256) {
    int i = idx >> 4, j = idx & 15;
    if (j < nq) basem[(size_t)i * NBUCK + q0 + j] = s[i][j];
  }
}

// ---------- C: exclusive scan of bucket totals ----------
__global__ void k_scanq(const int* __restrict__ btot, int* __restrict__ gbase) {
  __shared__ int s[NBUCK];
  __shared__ int c[256];
  const int NCH = (NBUCK + 3) / 4;
  int t = threadIdx.x;
  for (int i = t; i < NBUCK; i += 256) s[i] = btot[i];
  __syncthreads();
  if (t < NCH) {
    int b0 = 4 * t, sum = 0;
    #pragma unroll
    for (int j = 0; j < 4; ++j) if (b0 + j < NBUCK) sum += s[b0 + j];
    c[t] = sum;
  }
  __syncthreads();
  for (int d = 1; d < NCH; d <<= 1) {
    int v = (t < NCH && t >= d) ? c[t - d] : 0;
    __syncthreads();
    if (t < NCH) c[t] += v;
    __syncthreads();
  }
  if (t < NCH) {
    int b0 = 4 * t;
    int run = (t > 0) ? c[t - 1] : 0;
    #pragma unroll
    for (int j = 0; j < 4; ++j)
      if (b0 + j < NBUCK) { int v = s[b0 + j]; s[b0 + j] = run; run += v; }
  }
  __syncthreads();
  for (int i = t; i < NBUCK; i += 256) gbase[i] = s[i];
}

// ---------- D: scatter via LDS sort-stage (counts from basem diff) ----------
__global__ void k_scat(const int* __restrict__ row, const int* __restrict__ col,
                       const float* __restrict__ ew, const int* __restrict__ basem,
                       const int* __restrict__ gbase, int2* __restrict__ bin) {
  __shared__ int segB[NBUCK];
  __shared__ int cnt[NBUCK];
  __shared__ int csc[256];
  __shared__ int2 stage[EPB];
  __shared__ unsigned short qarr[EPB];
  int b = blockIdx.x, t = threadIdx.x;
  const int* rowA = basem + (size_t)b * NBUCK;
  const int* rowB = basem + (size_t)(b + 1) * NBUCK;
  for (int i = t; i < NBUCK; i += 256) {
    int a = rowA[i];
    segB[i] = gbase[i] + a;
    cnt[i] = rowB[i] - a;
  }
  __syncthreads();
  const int NCH = (NBUCK + 3) / 4;
  int q4 = 4 * t;
  if (t < NCH) {
    int sum = 0;
    #pragma unroll
    for (int j = 0; j < 4; ++j) if (q4 + j < NBUCK) sum += cnt[q4 + j];
    csc[t] = sum;
  }
  __syncthreads();
  for (int d = 1; d < NCH; d <<= 1) {
    int v = (t < NCH && t >= d) ? csc[t - d] : 0;
    __syncthreads();
    if (t < NCH) csc[t] += v;
    __syncthreads();
  }
  if (t < NCH) {
    int run = (t > 0) ? csc[t - 1] : 0;
    #pragma unroll
    for (int j = 0; j < 4; ++j)
      if (q4 + j < NBUCK) {
        int v = cnt[q4 + j];
        segB[q4 + j] -= run;
        cnt[q4 + j] = run;
        run += v;
      }
  }
  __syncthreads();
  int e0 = b * EPB;
  int nE = min(EPB, NE - e0);
  for (int i = t; i < nE; i += 256) {
    int e = e0 + i;
    int cc = col[e], q = cc >> 7;
    int p = atomicAdd(&cnt[q], 1);
    stage[p] = make_int2(row[e] | ((cc & 127) << 17), __float_as_int(ew[e]));
    qarr[p] = (unsigned short)q;
  }
  __syncthreads();
  for (int p = t; p < nE; p += 256) {
    int q = qarr[p];
    bin[segB[q] + p] = stage[p];
  }
}

// ---------- E: counting sort -> CSR (old rows) + degree-sorted relabel maps ----------
__global__ void k_build(const int* __restrict__ gbase, const int* __restrict__ btot,
                        const int2* __restrict__ bin,
                        int* __restrict__ csr, float* __restrict__ dis,
                        int* __restrict__ nstart, int* __restrict__ ncnt,
                        int* __restrict__ perm, int* __restrict__ iperm) {
  __shared__ int2 stage[SCAP];
  __shared__ int cnt[128];
  __shared__ float degw[128];
  __shared__ int off[129];
  __shared__ int dh[129];
  int b = blockIdx.x;
  int gb0 = gbase[b];
  int nb = btot[b];
  const int2* gb = bin + gb0;
  for (int i = threadIdx.x; i < 128; i += 256) { cnt[i] = 0; degw[i] = 0.f; }
  for (int i = threadIdx.x; i < 129; i += 256) dh[i] = 0;
  __syncthreads();
  for (int i = threadIdx.x; i < nb; i += 256) {
    int2 v = gb[i];
    if (i < SCAP) stage[i] = v;
    int c = (v.x >> 17) & 127;
    atomicAdd(&cnt[c], 1);
    atomicAdd(&degw[c], __int_as_float(v.y));
  }
  __syncthreads();
  if (threadIdx.x == 0) {
    int s = 0;
    for (int c = 0; c < 128; ++c) { off[c] = s; s += cnt[c]; }
    off[128] = s;
  }
  __syncthreads();
  for (int c = threadIdx.x; c < 128; c += 256) {
    int n = b * 128 + c;
    if (n < NN) atomicAdd(&dh[min(cnt[c], 127) + 1], 1);
  }
  __syncthreads();
  if (threadIdx.x == 0) {
    for (int d = 1; d < 129; ++d) dh[d] += dh[d - 1];
  }
  __syncthreads();
  for (int c = threadIdx.x; c < 128; c += 256) {
    int n = b * 128 + c;
    if (n < NN) {
      int r = atomicAdd(&dh[min(cnt[c], 127)], 1);  // rank, ascending degree
      int nw = b * 128 + r;                         // new id
      perm[nw] = n;
      iperm[n] = nw;
      nstart[nw] = gb0 + off[c];
      ncnt[nw] = cnt[c];
      float d = degw[c];
      dis[nw] = (d > 0.f) ? rsqrtf(fmaxf(d, 1e-12f)) : 0.f;
    }
  }
  __syncthreads();
  for (int i = threadIdx.x; i < 128; i += 256) cnt[i] = 0;
  __syncthreads();
  int* cb = csr + gb0;
  for (int i = threadIdx.x; i < nb; i += 256) {
    int2 v = (i < SCAP) ? stage[i] : gb[i];
    int c = (v.x >> 17) & 127;
    int pos = off[c] + atomicAdd(&cnt[c], 1);
    unsigned u = (unsigned)v.y;
    u += 0xFFFFu + ((u >> 17) & 1);  // RN to 15-bit weight
    cb[pos] = (v.x & 0x1FFFF) | (int)(u & 0xFFFE0000u);  // OLD row id
  }
}

// ---------- F: remap CSR row field old -> new id ----------
__global__ void k_relab(int* __restrict__ csr, const int* __restrict__ iperm) {
  int i = blockIdx.x * 256 + threadIdx.x;
  if (i < NE) {
    int e = csr[i];
    csr[i] = (int)((unsigned)e & 0xFFFE0000u) | iperm[e & 0x1FFFF];
  }
}

// ---------- conv1 (all arrays in new-id space) ----------
__global__ void k_init1(const float* __restrict__ x, const float* __restrict__ rw,
                        const float* __restrict__ bias, const float* __restrict__ dis,
                        const int* __restrict__ perm,
                        unsigned short* __restrict__ root1, float* __restrict__ s) {
  int idx = blockIdx.x * 256 + threadIdx.x;  // n*16 + f (n = new id)
  if (idx >= NN * 16) return;
  int n = idx >> 4, f = idx & 15;
  float xv = x[perm[n]];
  if (f == 0) s[n] = dis[n] * xv;
  root1[n * 48 + f]      = f2bf(xv * rw[f]      + bias[f]);
  root1[n * 48 + 16 + f] = f2bf(xv * rw[16 + f] + bias[16 + f]);
  root1[n * 48 + 32 + f] = f2bf(xv * rw[32 + f] + bias[32 + f]);
}

// Pass 1 exploits rank-1 input: gather is a SCALAR sum g = sum_e w_e*dis_r*x_r.
__global__ void k_prop_first(const float* __restrict__ s,
                             const unsigned short* __restrict__ root,
                             ushort4* __restrict__ outp, const int* __restrict__ csr,
                             const int* __restrict__ nstart, const int* __restrict__ ncnt,
                             const float* __restrict__ dis, const float* __restrict__ w,
                             const float* __restrict__ iw) {
  __shared__ float ws[768];
  for (int i = threadIdx.x; i < 768; i += 256) ws[i] = w[i];
  __syncthreads();
  int f = threadIdx.x & 15;
  int n = (blockIdx.x * 256 + threadIdx.x) >> 4;
  if (n >= NN) return;
  int e0 = nstart[n], cnt = ncnt[n];
  float g = 0.f;
  for (int i = f; i < cnt; i += 16) {
    int e = csr[e0 + i];
    g = fmaf(edgew(e), s[e & 0x1FFFF], g);
  }
  #pragma unroll
  for (int d = 8; d; d >>= 1) g += __shfl_xor(g, d, 16);
  float dn = dis[n];
  float dg = dn * g;
  float a0 = fmaxf(fmaf(dg, iw[f],      bf2f(root[n * 48 + f])),      0.f);
  float a1 = fmaxf(fmaf(dg, iw[16 + f], bf2f(root[n * 48 + 16 + f])), 0.f);
  float a2 = fmaxf(fmaf(dg, iw[32 + f], bf2f(root[n * 48 + 32 + f])), 0.f);
  float n0 = 0.f, n1 = 0.f, n2 = 0.f;
  #pragma unroll
  for (int f2 = 0; f2 < 16; ++f2) {
    float b0 = __shfl(a0, f2, 16);
    float b1 = __shfl(a1, f2, 16);
    float b2v = __shfl(a2, f2, 16);
    n0 = fmaf(b0, ws[f2 * 16 + f], n0);
    n1 = fmaf(b1, ws[256 + f2 * 16 + f], n1);
    n2 = fmaf(b2v, ws[512 + f2 * 16 + f], n2);
  }
  ushort4 pk;
  pk.x = f2bf(dn * n0); pk.y = f2bf(dn * n1); pk.z = f2bf(dn * n2); pk.w = 0;
  outp[(size_t)n * 16 + f] = pk;
}

// 16 lanes per dest node; ids are degree-sorted within buckets (balanced waves).
template <bool APPLY_W>
__global__ void k_prop16(const ushort4* __restrict__ in,
                         const unsigned short* __restrict__ root,
                         ushort4* __restrict__ outp, const int* __restrict__ csr,
                         const int* __restrict__ nstart, const int* __restrict__ ncnt,
                         const float* __restrict__ dis, const float* __restrict__ w,
                         const float* __restrict__ bng, const float* __restrict__ bnb,
                         const float* __restrict__ bnm, const float* __restrict__ bnv,
                         const float* __restrict__ iw2, const float* __restrict__ rw2,
                         const float* __restrict__ b2,
                         float4* __restrict__ root2, ushort4* __restrict__ o2) {
  __shared__ float ws[768];
  if (APPLY_W) {
    for (int i = threadIdx.x; i < 768; i += 256) ws[i] = w[i];
    __syncthreads();
  }
  int f = threadIdx.x & 15;
  int n = (blockIdx.x * 256 + threadIdx.x) >> 4;
  if (n >= NN) return;
  int e0 = nstart[n], cnt = ncnt[n];
  float a0 = 0.f, a1 = 0.f, a2 = 0.f;
  int i = 0;
  for (; i + 8 <= cnt; i += 8) {
    int e[8];
    ushort4 v[8];
    #pragma unroll
    for (int j = 0; j < 8; ++j) e[j] = csr[e0 + i + j];
    #pragma unroll
    for (int j = 0; j < 8; ++j) v[j] = in[(size_t)(e[j] & 0x1FFFF) * 16 + f];
    #pragma unroll
    for (int j = 0; j < 8; ++j) {
      float we = edgew(e[j]);
      a0 = fmaf(we, bf2f(v[j].x), a0);
      a1 = fmaf(we, bf2f(v[j].y), a1);
      a2 = fmaf(we, bf2f(v[j].z), a2);
    }
  }
  for (; i + 4 <= cnt; i += 4) {
    int e[4];
    ushort4 v[4];
    #pragma unroll
    for (int j = 0; j < 4; ++j) e[j] = csr[e0 + i + j];
    #pragma unroll
    for (int j = 0; j < 4; ++j) v[j] = in[(size_t)(e[j] & 0x1FFFF) * 16 + f];
    #pragma unroll
    for (int j = 0; j < 4; ++j) {
      float we = edgew(e[j]);
      a0 = fmaf(we, bf2f(v[j].x), a0);
      a1 = fmaf(we, bf2f(v[j].y), a1);
      a2 = fmaf(we, bf2f(v[j].z), a2);
    }
  }
  for (; i < cnt; ++i) {
    int e = csr[e0 + i];
    float we = edgew(e);
    ushort4 v = in[(size_t)(e & 0x1FFFF) * 16 + f];
    a0 = fmaf(we, bf2f(v.x), a0);
    a1 = fmaf(we, bf2f(v.y), a1);
    a2 = fmaf(we, bf2f(v.z), a2);
  }
  float dn = dis[n];
  a0 = fmaxf(fmaf(dn, a0, bf2f(root[n * 48 + f])),      0.f);
  a1 = fmaxf(fmaf(dn, a1, bf2f(root[n * 48 + 16 + f])), 0.f);
  a2 = fmaxf(fmaf(dn, a2, bf2f(root[n * 48 + 32 + f])), 0.f);
  if (APPLY_W) {
    float n0 = 0.f, n1 = 0.f, n2 = 0.f;
    #pragma unroll
    for (int f2 = 0; f2 < 16; ++f2) {
      float b0 = __shfl(a0, f2, 16);
      float b1 = __shfl(a1, f2, 16);
      float b2v = __shfl(a2, f2, 16);
      n0 = fmaf(b0, ws[f2 * 16 + f], n0);
      n1 = fmaf(b1, ws[256 + f2 * 16 + f], n1);
      n2 = fmaf(b2v, ws[512 + f2 * 16 + f], n2);
    }
    ushort4 pk;
    pk.x = f2bf(dn * n0); pk.y = f2bf(dn * n1); pk.z = f2bf(dn * n2); pk.w = 0;
    outp[(size_t)n * 16 + f] = pk;
  } else {
    float mean = (a0 + a1 + a2) * (1.f / 3.f);
    float hv = fmaxf((mean - bnm[f]) * rsqrtf(bnv[f] + BN_EPS) * bng[f] + bnb[f], 0.f);
    float d0 = hv * iw2[f],      r0 = hv * rw2[f];
    float d1 = hv * iw2[16 + f], r1 = hv * rw2[16 + f];
    float d2 = hv * iw2[32 + f], r2 = hv * rw2[32 + f];
    #pragma unroll
    for (int d = 8; d; d >>= 1) {
      d0 += __shfl_xor(d0, d, 16); r0 += __shfl_xor(r0, d, 16);
      d1 += __shfl_xor(d1, d, 16); r1 += __shfl_xor(r1, d, 16);
      d2 += __shfl_xor(d2, d, 16); r2 += __shfl_xor(r2, d, 16);
    }
    if (f == 0) {
      float4 rt;
      rt.x = r0 + b2[0]; rt.y = r1 + b2[1]; rt.z = r2 + b2[2]; rt.w = 0.f;
      root2[n] = rt;
      ushort4 pk;
      pk.x = f2bf(dn * d0); pk.y = f2bf(dn * d1); pk.z = f2bf(dn * d2); pk.w = 0;
      o2[n] = pk;
    }
  }
}

// ---------- conv2: 16 lanes split edges; state bf16 ushort4 ----------
template <bool LAST>
__global__ void k_prop1(const ushort4* __restrict__ in, const float4* __restrict__ root,
                        ushort4* __restrict__ outp, float* __restrict__ outf,
                        const int* __restrict__ csr,
                        const int* __restrict__ nstart, const int* __restrict__ ncnt,
                        const float* __restrict__ dis, const float* __restrict__ w2,
                        const int* __restrict__ perm) {
  int lane = threadIdx.x & 15;
  int n = (blockIdx.x * 256 + threadIdx.x) >> 4;
  if (n >= NN) return;
  int e0 = nstart[n], cnt = ncnt[n];
  float a0 = 0.f, a1 = 0.f, a2 = 0.f;
  for (int i = lane; i < cnt; i += 16) {
    int e = csr[e0 + i];
    float we = edgew(e);
    ushort4 src = in[e & 0x1FFFF];
    a0 = fmaf(we, bf2f(src.x), a0);
    a1 = fmaf(we, bf2f(src.y), a1);
    a2 = fmaf(we, bf2f(src.z), a2);
  }
  #pragma unroll
  for (int d = 8; d; d >>= 1) {
    a0 += __shfl_xor(a0, d, 16);
    a1 += __shfl_xor(a1, d, 16);
    a2 += __shfl_xor(a2, d, 16);
  }
  if (lane == 0) {
    float dn = dis[n];
    float4 rt = root[n];
    if (LAST) {
      float s = fmaf(dn, a0, rt.x) + fmaf(dn, a1, rt.y) + fmaf(dn, a2, rt.z);
      s *= (1.f / 3.f);
      outf[perm[n]] = 1.f / (1.f + expf(-s));  // scatter back to original ids
    } else {
      ushort4 pk;
      pk.x = f2bf(dn * fmaf(dn, a0, rt.x) * w2[0]);
      pk.y = f2bf(dn * fmaf(dn, a1, rt.y) * w2[1]);
      pk.z = f2bf(dn * fmaf(dn, a2, rt.z) * w2[2]);
      pk.w = 0;
      outp[n] = pk;
    }
  }
}

// ---------- launch ----------
extern "C" void kernel_launch(void* const* d_in, const int* in_sizes, int n_in,
                              void* d_out, int out_size, void* d_ws, size_t ws_size,
                              hipStream_t stream) {
  const float* x     = (const float*)d_in[0];
  const int*   ei    = (const int*)d_in[1];
  const float* ew    = (const float*)d_in[2];
  const float* c1_iw = (const float*)d_in[3];
  const float* c1_w  = (const float*)d_in[4];
  const float* c1_rw = (const float*)d_in[5];
  const float* c1_b  = (const float*)d_in[6];
  const float* bn_g  = (const float*)d_in[7];
  const float* bn_b  = (const float*)d_in[8];
  const float* bn_m  = (const float*)d_in[9];
  const float* bn_v  = (const float*)d_in[10];
  const float* c2_iw = (const float*)d_in[11];
  const float* c2_w  = (const float*)d_in[12];
  const float* c2_rw = (const float*)d_in[13];
  const float* c2_b  = (const float*)d_in[14];
  float* out = (float*)d_out;

  char* p = (char*)d_ws;
  auto take = [&](size_t bytes) -> char* { char* r = p; p += alignup(bytes); return r; };
  int*     cntm   = (int*)take((size_t)NBLK * NBUCK * 4);
  int*     basem  = (int*)take((size_t)(NBLK + 1) * NBUCK * 4);
  int*     btot   = (int*)take((size_t)NBUCK * 4);
  int*     gbase  = (int*)take((size_t)NBUCK * 4);
  int2*    bin    = (int2*)take((size_t)NE * 8);
  int*     csr    = (int*)take((size_t)NE * 4);
  float*   dis    = (float*)take((size_t)NN * 4);
  int*     nst    = (int*)take((size_t)NN * 4);
  int*     ncn    = (int*)take((size_t)NN * 4);
  int*     perm   = (int*)take((size_t)NN * 4);
  int*     iperm  = (int*)take((size_t)NN * 4);
  unsigned short* root1 = (unsigned short*)take((size_t)NN * 48 * 2);
  float*   sbuf   = (float*)take((size_t)NN * 4);
  ushort4* bufA   = (ushort4*)take((size_t)NN * 16 * 8);
  ushort4* bufB   = (ushort4*)take((size_t)NN * 16 * 8);
  float4*  root2  = (float4*)take((size_t)NN * 16);
  ushort4* o2A    = (ushort4*)take((size_t)NN * 8);
  ushort4* o2B    = (ushort4*)take((size_t)NN * 8);

  const int* row = ei;
  const int* col = ei + NE;

  const int gP = (NN * 16 + 255) / 256;
  const int gSB = (NBUCK + SB_Q - 1) / SB_Q;
  const int gE = (NE + 255) / 256;

  k_hist <<<NBLK, 256, 0, stream>>>(col, cntm);
  k_scanb<<<gSB, 256, 0, stream>>>(cntm, basem, btot);
  k_scanq<<<1, 256, 0, stream>>>(btot, gbase);
  k_scat <<<NBLK, 256, 0, stream>>>(row, col, ew, basem, gbase, bin);
  k_build<<<NBUCK, 256, 0, stream>>>(gbase, btot, bin, csr, dis, nst, ncn, perm, iperm);
  k_relab<<<gE, 256, 0, stream>>>(csr, iperm);

  k_init1<<<gP, 256, 0, stream>>>(x, c1_rw, c1_b, dis, perm, root1, sbuf);
  k_prop_first<<<gP, 256, 0, stream>>>(sbuf, root1, bufA, csr, nst, ncn, dis, c1_w, c1_iw);
  k_prop16<true ><<<gP, 256, 0, stream>>>(bufA, root1, bufB, csr, nst, ncn, dis, c1_w,
      nullptr, nullptr, nullptr, nullptr, nullptr, nullptr, nullptr, nullptr, nullptr);
  k_prop16<true ><<<gP, 256, 0, stream>>>(bufB, root1, bufA, csr, nst, ncn, dis, c1_w,
      nullptr, nullptr, nullptr, nullptr, nullptr, nullptr, nullptr, nullptr, nullptr);
  k_prop16<false><<<gP, 256, 0, stream>>>(bufA, root1, nullptr, csr, nst, ncn, dis, nullptr,
      bn_g, bn_b, bn_m, bn_v, c2_iw, c2_rw, c2_b, root2, o2A);

  k_prop1<false><<<gP, 256, 0, stream>>>(o2A, root2, o2B, nullptr, csr, nst, ncn, dis, c2_w, perm);
  k_prop1<false><<<gP, 256, 0, stream>>>(o2B, root2, o2A, nullptr, csr, nst, ncn, dis, c2_w, perm);
  k_prop1<false><<<gP, 256, 0, stream>>>(o2A, root2, o2B, nullptr, csr, nst, ncn, dis, c2_w, perm);
  k_prop1<true ><<<gP, 256, 0, stream>>>(o2B, root2, nullptr, out, csr, nst, ncn, dis, c2_w, perm);
}

// Round 14
// 383.355 us; speedup vs baseline: 1.1564x; 1.1536x over previous
//
#include <hip/hip_runtime.h>
#include <math.h>

#define NN 100000
#define NE 3200000
#define NBUCK 782   // buckets of 128 cols
#define EPB 4096    // edges per partition block
#define NBLK 782    // ceil(NE/EPB)
#define SB_Q 16     // buckets per k_scanb block
#define SCAP 4608   // k_build LDS stage capacity (mean 4092, +8 sigma)
#define BN_EPS 1e-5f

static inline size_t alignup(size_t v) { return (v + 255) & ~size_t(255); }

__device__ inline unsigned short f2bf(float x) {  // round-to-nearest bf16
  unsigned u = __float_as_uint(x);
  u += 0x7FFF + ((u >> 16) & 1);
  return (unsigned short)(u >> 16);
}
__device__ inline float bf2f(unsigned short h) {
  return __uint_as_float((unsigned)h << 16);
}
// edge entry: bits[16:0]=row, bits[31:17]=top 15 bits of fp32 weight (RN)
__device__ inline float edgew(int e) {
  return __uint_as_float((unsigned)e & 0xFFFE0000u);
}
__device__ inline int packent(int r, float w) {  // row | RN15(w)
  unsigned u = __float_as_uint(w);
  u += 0xFFFFu + ((u >> 17) & 1);
  return r | (int)(u & 0xFFFE0000u);
}

// ---------- A: per-block bucket histogram ----------
__global__ void k_hist(const int* __restrict__ col, int* __restrict__ cntm) {
  __shared__ int cnt[NBUCK];
  for (int i = threadIdx.x; i < NBUCK; i += 256) cnt[i] = 0;
  __syncthreads();
  int e0 = blockIdx.x * EPB;
  int nE = min(EPB, NE - e0);
  for (int i = threadIdx.x; i < nE; i += 256) atomicAdd(&cnt[col[e0 + i] >> 7], 1);
  __syncthreads();
  int* dst = cntm + (size_t)blockIdx.x * NBUCK;
  for (int i = threadIdx.x; i < NBUCK; i += 256) dst[i] = cnt[i];
}

// ---------- B: per-bucket exclusive scan over blocks (+ total row NBLK) ----------
__global__ void k_scanb(const int* __restrict__ cntm, int* __restrict__ basem,
                        int* __restrict__ btot) {
  __shared__ int s[NBLK][SB_Q + 1];
  int q0 = blockIdx.x * SB_Q;
  int nq = min(SB_Q, NBUCK - q0);
  int t = threadIdx.x;
  for (int idx = t; idx < NBLK * SB_Q; idx += 256) {
    int i = idx >> 4, j = idx & 15;
    s[i][j] = (j < nq) ? cntm[(size_t)i * NBUCK + q0 + j] : 0;
  }
  __syncthreads();
  int wave = t >> 6, lane = t & 63;
  for (int j = wave; j < SB_Q; j += 4) {
    int carry = 0;
    for (int c = 0; c < (NBLK + 63) / 64; ++c) {
      int i = c * 64 + lane;
      int v = (i < NBLK) ? s[i][j] : 0;
      int x = v;
      #pragma unroll
      for (int d = 1; d < 64; d <<= 1) {
        int tt = __shfl_up(x, d, 64);
        if (lane >= d) x += tt;
      }
      if (i < NBLK) s[i][j] = x - v + carry;
      carry += __shfl(x, 63, 64);
    }
    if (lane == 0 && j < nq) {
      btot[q0 + j] = carry;
      basem[(size_t)NBLK * NBUCK + q0 + j] = carry;  // total row
    }
  }
  __syncthreads();
  for (int idx = t; idx < NBLK * SB_Q; idx += 256) {
    int i = idx >> 4, j = idx & 15;
    if (j < nq) basem[(size_t)i * NBUCK + q0 + j] = s[i][j];
  }
}

// ---------- C: exclusive scan of bucket totals ----------
__global__ void k_scanq(const int* __restrict__ btot, int* __restrict__ gbase) {
  __shared__ int s[NBUCK];
  __shared__ int c[256];
  const int NCH = (NBUCK + 3) / 4;
  int t = threadIdx.x;
  for (int i = t; i < NBUCK; i += 256) s[i] = btot[i];
  __syncthreads();
  if (t < NCH) {
    int b0 = 4 * t, sum = 0;
    #pragma unroll
    for (int j = 0; j < 4; ++j) if (b0 + j < NBUCK) sum += s[b0 + j];
    c[t] = sum;
  }
  __syncthreads();
  for (int d = 1; d < NCH; d <<= 1) {
    int v = (t < NCH && t >= d) ? c[t - d] : 0;
    __syncthreads();
    if (t < NCH) c[t] += v;
    __syncthreads();
  }
  if (t < NCH) {
    int b0 = 4 * t;
    int run = (t > 0) ? c[t - 1] : 0;
    #pragma unroll
    for (int j = 0; j < 4; ++j)
      if (b0 + j < NBUCK) { int v = s[b0 + j]; s[b0 + j] = run; run += v; }
  }
  __syncthreads();
  for (int i = t; i < NBUCK; i += 256) gbase[i] = s[i];
}

// ---------- D: scatter -> final 4B entries + 1B bucket-local cols ----------
__global__ void k_scat(const int* __restrict__ row, const int* __restrict__ col,
                       const float* __restrict__ ew, const int* __restrict__ basem,
                       const int* __restrict__ gbase, int* __restrict__ csrT,
                       unsigned char* __restrict__ colb) {
  __shared__ int segB[NBUCK];
  __shared__ int cnt[NBUCK];
  __shared__ int csc[256];
  __shared__ int stage[EPB];
  __shared__ unsigned char stc[EPB];
  __shared__ unsigned short qarr[EPB];
  int b = blockIdx.x, t = threadIdx.x;
  const int* rowA = basem + (size_t)b * NBUCK;
  const int* rowB = basem + (size_t)(b + 1) * NBUCK;
  for (int i = t; i < NBUCK; i += 256) {
    int a = rowA[i];
    segB[i] = gbase[i] + a;
    cnt[i] = rowB[i] - a;
  }
  __syncthreads();
  const int NCH = (NBUCK + 3) / 4;
  int q4 = 4 * t;
  if (t < NCH) {
    int sum = 0;
    #pragma unroll
    for (int j = 0; j < 4; ++j) if (q4 + j < NBUCK) sum += cnt[q4 + j];
    csc[t] = sum;
  }
  __syncthreads();
  for (int d = 1; d < NCH; d <<= 1) {
    int v = (t < NCH && t >= d) ? csc[t - d] : 0;
    __syncthreads();
    if (t < NCH) csc[t] += v;
    __syncthreads();
  }
  if (t < NCH) {
    int run = (t > 0) ? csc[t - 1] : 0;
    #pragma unroll
    for (int j = 0; j < 4; ++j)
      if (q4 + j < NBUCK) {
        int v = cnt[q4 + j];
        segB[q4 + j] -= run;
        cnt[q4 + j] = run;
        run += v;
      }
  }
  __syncthreads();
  int e0 = b * EPB;
  int nE = min(EPB, NE - e0);
  for (int i = t; i < nE; i += 256) {
    int e = e0 + i;
    int cc = col[e], q = cc >> 7;
    int p = atomicAdd(&cnt[q], 1);
    stage[p] = packent(row[e], ew[e]);
    stc[p] = (unsigned char)(cc & 127);
    qarr[p] = (unsigned short)q;
  }
  __syncthreads();
  for (int p = t; p < nE; p += 256) {
    int q = qarr[p];
    int dst = segB[q] + p;
    csrT[dst] = stage[p];
    colb[dst] = stc[p];
  }
}

// ---------- E: per-bucket counting sort (4B entries + col bytes) ----------
__global__ void k_build(const int* __restrict__ gbase, const int* __restrict__ btot,
                        const int* __restrict__ csrT, const unsigned char* __restrict__ colb,
                        int* __restrict__ csr, float* __restrict__ dis,
                        int* __restrict__ nstart, int* __restrict__ ncnt) {
  __shared__ int stage[SCAP];
  __shared__ unsigned char scol[SCAP];
  __shared__ int cnt[128];
  __shared__ float degw[128];
  __shared__ int off[129];
  int b = blockIdx.x;
  int gb0 = gbase[b];
  int nb = btot[b];
  const int* ct = csrT + gb0;
  const unsigned char* cbv = colb + gb0;
  for (int i = threadIdx.x; i < 128; i += 256) { cnt[i] = 0; degw[i] = 0.f; }
  __syncthreads();
  for (int i = threadIdx.x; i < nb; i += 256) {
    int v = ct[i];
    unsigned char c = cbv[i];
    if (i < SCAP) { stage[i] = v; scol[i] = c; }
    atomicAdd(&cnt[c], 1);
    atomicAdd(&degw[c], edgew(v));  // 15-bit weight: rel err ~2^-9, fine for rsqrt
  }
  __syncthreads();
  if (threadIdx.x == 0) {
    int s = 0;
    for (int c = 0; c < 128; ++c) { off[c] = s; s += cnt[c]; }
    off[128] = s;
  }
  __syncthreads();
  for (int c = threadIdx.x; c < 128; c += 256) {
    int n = b * 128 + c;
    if (n < NN) {
      nstart[n] = gb0 + off[c];
      ncnt[n] = cnt[c];
      float d = degw[c];
      dis[n] = (d > 0.f) ? rsqrtf(fmaxf(d, 1e-12f)) : 0.f;
    }
  }
  __syncthreads();
  for (int i = threadIdx.x; i < 128; i += 256) cnt[i] = 0;
  __syncthreads();
  int* cb = csr + gb0;
  for (int i = threadIdx.x; i < nb; i += 256) {
    int v; unsigned char c;
    if (i < SCAP) { v = stage[i]; c = scol[i]; }
    else { v = ct[i]; c = cbv[i]; }
    int pos = off[c] + atomicAdd(&cnt[c], 1);
    cb[pos] = v;
  }
}

// ---------- conv1 ----------
__global__ void k_init1(const float* __restrict__ x, const float* __restrict__ rw,
                        const float* __restrict__ bias, const float* __restrict__ dis,
                        unsigned short* __restrict__ root1, float* __restrict__ s) {
  int idx = blockIdx.x * 256 + threadIdx.x;  // n*16 + f
  if (idx >= NN * 16) return;
  int n = idx >> 4, f = idx & 15;
  float xv = x[n];
  if (f == 0) s[n] = dis[n] * xv;
  root1[n * 48 + f]      = f2bf(xv * rw[f]      + bias[f]);
  root1[n * 48 + 16 + f] = f2bf(xv * rw[16 + f] + bias[16 + f]);
  root1[n * 48 + 32 + f] = f2bf(xv * rw[32 + f] + bias[32 + f]);
}

// Pass 1 exploits rank-1 input: gather is a SCALAR sum g = sum_e w_e*dis_r*x_r.
__global__ void k_prop_first(const float* __restrict__ s,
                             const unsigned short* __restrict__ root,
                             ushort4* __restrict__ outp, const int* __restrict__ csr,
                             const int* __restrict__ nstart, const int* __restrict__ ncnt,
                             const float* __restrict__ dis, const float* __restrict__ w,
                             const float* __restrict__ iw) {
  __shared__ float ws[768];
  for (int i = threadIdx.x; i < 768; i += 256) ws[i] = w[i];
  __syncthreads();
  int f = threadIdx.x & 15;
  int n = (blockIdx.x * 256 + threadIdx.x) >> 4;
  if (n >= NN) return;
  int e0 = nstart[n], cnt = ncnt[n];
  float g = 0.f;
  for (int i = f; i < cnt; i += 16) {
    int e = csr[e0 + i];
    g = fmaf(edgew(e), s[e & 0x1FFFF], g);
  }
  #pragma unroll
  for (int d = 8; d; d >>= 1) g += __shfl_xor(g, d, 16);
  float dn = dis[n];
  float dg = dn * g;
  float a0 = fmaxf(fmaf(dg, iw[f],      bf2f(root[n * 48 + f])),      0.f);
  float a1 = fmaxf(fmaf(dg, iw[16 + f], bf2f(root[n * 48 + 16 + f])), 0.f);
  float a2 = fmaxf(fmaf(dg, iw[32 + f], bf2f(root[n * 48 + 32 + f])), 0.f);
  float n0 = 0.f, n1 = 0.f, n2 = 0.f;
  #pragma unroll
  for (int f2 = 0; f2 < 16; ++f2) {
    float b0 = __shfl(a0, f2, 16);
    float b1 = __shfl(a1, f2, 16);
    float b2v = __shfl(a2, f2, 16);
    n0 = fmaf(b0, ws[f2 * 16 + f], n0);
    n1 = fmaf(b1, ws[256 + f2 * 16 + f], n1);
    n2 = fmaf(b2v, ws[512 + f2 * 16 + f], n2);
  }
  ushort4 pk;
  pk.x = f2bf(dn * n0); pk.y = f2bf(dn * n1); pk.z = f2bf(dn * n2); pk.w = 0;
  outp[(size_t)n * 16 + f] = pk;
}

// 16 lanes per dest node; lane = feature (R11 config: measured best).
template <bool APPLY_W>
__global__ __launch_bounds__(256, 6)
void k_prop16(const ushort4* __restrict__ in,
              const unsigned short* __restrict__ root,
              ushort4* __restrict__ outp, const int* __restrict__ csr,
              const int* __restrict__ nstart, const int* __restrict__ ncnt,
              const float* __restrict__ dis, const float* __restrict__ w,
              const float* __restrict__ bng, const float* __restrict__ bnb,
              const float* __restrict__ bnm, const float* __restrict__ bnv,
              const float* __restrict__ iw2, const float* __restrict__ rw2,
              const float* __restrict__ b2,
              float4* __restrict__ root2, ushort4* __restrict__ o2) {
  __shared__ float ws[768];
  if (APPLY_W) {
    for (int i = threadIdx.x; i < 768; i += 256) ws[i] = w[i];
    __syncthreads();
  }
  int f = threadIdx.x & 15;
  int n = (blockIdx.x * 256 + threadIdx.x) >> 4;
  if (n >= NN) return;
  int e0 = nstart[n], cnt = ncnt[n];
  float a0 = 0.f, a1 = 0.f, a2 = 0.f;
  int i = 0;
  for (; i + 16 <= cnt; i += 16) {
    int e[16];
    ushort4 v[16];
    #pragma unroll
    for (int j = 0; j < 16; ++j) e[j] = csr[e0 + i + j];
    #pragma unroll
    for (int j = 0; j < 16; ++j) v[j] = in[(size_t)(e[j] & 0x1FFFF) * 16 + f];
    #pragma unroll
    for (int j = 0; j < 16; ++j) {
      float we = edgew(e[j]);
      a0 = fmaf(we, bf2f(v[j].x), a0);
      a1 = fmaf(we, bf2f(v[j].y), a1);
      a2 = fmaf(we, bf2f(v[j].z), a2);
    }
  }
  for (; i + 4 <= cnt; i += 4) {
    int e[4];
    ushort4 v[4];
    #pragma unroll
    for (int j = 0; j < 4; ++j) e[j] = csr[e0 + i + j];
    #pragma unroll
    for (int j = 0; j < 4; ++j) v[j] = in[(size_t)(e[j] & 0x1FFFF) * 16 + f];
    #pragma unroll
    for (int j = 0; j < 4; ++j) {
      float we = edgew(e[j]);
      a0 = fmaf(we, bf2f(v[j].x), a0);
      a1 = fmaf(we, bf2f(v[j].y), a1);
      a2 = fmaf(we, bf2f(v[j].z), a2);
    }
  }
  for (; i < cnt; ++i) {
    int e = csr[e0 + i];
    float we = edgew(e);
    ushort4 v = in[(size_t)(e & 0x1FFFF) * 16 + f];
    a0 = fmaf(we, bf2f(v.x), a0);
    a1 = fmaf(we, bf2f(v.y), a1);
    a2 = fmaf(we, bf2f(v.z), a2);
  }
  float dn = dis[n];
  a0 = fmaxf(fmaf(dn, a0, bf2f(root[n * 48 + f])),      0.f);
  a1 = fmaxf(fmaf(dn, a1, bf2f(root[n * 48 + 16 + f])), 0.f);
  a2 = fmaxf(fmaf(dn, a2, bf2f(root[n * 48 + 32 + f])), 0.f);
  if (APPLY_W) {
    float n0 = 0.f, n1 = 0.f, n2 = 0.f;
    #pragma unroll
    for (int f2 = 0; f2 < 16; ++f2) {
      float b0 = __shfl(a0, f2, 16);
      float b1 = __shfl(a1, f2, 16);
      float b2v = __shfl(a2, f2, 16);
      n0 = fmaf(b0, ws[f2 * 16 + f], n0);
      n1 = fmaf(b1, ws[256 + f2 * 16 + f], n1);
      n2 = fmaf(b2v, ws[512 + f2 * 16 + f], n2);
    }
    ushort4 pk;
    pk.x = f2bf(dn * n0); pk.y = f2bf(dn * n1); pk.z = f2bf(dn * n2); pk.w = 0;
    outp[(size_t)n * 16 + f] = pk;
  } else {
    float mean = (a0 + a1 + a2) * (1.f / 3.f);
    float hv = fmaxf((mean - bnm[f]) * rsqrtf(bnv[f] + BN_EPS) * bng[f] + bnb[f], 0.f);
    float d0 = hv * iw2[f],      r0 = hv * rw2[f];
    float d1 = hv * iw2[16 + f], r1 = hv * rw2[16 + f];
    float d2 = hv * iw2[32 + f], r2 = hv * rw2[32 + f];
    #pragma unroll
    for (int d = 8; d; d >>= 1) {
      d0 += __shfl_xor(d0, d, 16); r0 += __shfl_xor(r0, d, 16);
      d1 += __shfl_xor(d1, d, 16); r1 += __shfl_xor(r1, d, 16);
      d2 += __shfl_xor(d2, d, 16); r2 += __shfl_xor(r2, d, 16);
    }
    if (f == 0) {
      float4 rt;
      rt.x = r0 + b2[0]; rt.y = r1 + b2[1]; rt.z = r2 + b2[2]; rt.w = 0.f;
      root2[n] = rt;
      ushort4 pk;
      pk.x = f2bf(dn * d0); pk.y = f2bf(dn * d1); pk.z = f2bf(dn * d2); pk.w = 0;
      o2[n] = pk;
    }
  }
}

// ---------- conv2: 16 lanes split edges; state bf16 ushort4 ----------
template <bool LAST>
__global__ void k_prop1(const ushort4* __restrict__ in, const float4* __restrict__ root,
                        ushort4* __restrict__ outp, float* __restrict__ outf,
                        const int* __restrict__ csr,
                        const int* __restrict__ nstart, const int* __restrict__ ncnt,
                        const float* __restrict__ dis, const float* __restrict__ w2) {
  int lane = threadIdx.x & 15;
  int n = (blockIdx.x * 256 + threadIdx.x) >> 4;
  if (n >= NN) return;
  int e0 = nstart[n], cnt = ncnt[n];
  float a0 = 0.f, a1 = 0.f, a2 = 0.f;
  for (int i = lane; i < cnt; i += 16) {
    int e = csr[e0 + i];
    float we = edgew(e);
    ushort4 src = in[e & 0x1FFFF];
    a0 = fmaf(we, bf2f(src.x), a0);
    a1 = fmaf(we, bf2f(src.y), a1);
    a2 = fmaf(we, bf2f(src.z), a2);
  }
  #pragma unroll
  for (int d = 8; d; d >>= 1) {
    a0 += __shfl_xor(a0, d, 16);
    a1 += __shfl_xor(a1, d, 16);
    a2 += __shfl_xor(a2, d, 16);
  }
  if (lane == 0) {
    float dn = dis[n];
    float4 rt = root[n];
    if (LAST) {
      float s = fmaf(dn, a0, rt.x) + fmaf(dn, a1, rt.y) + fmaf(dn, a2, rt.z);
      s *= (1.f / 3.f);
      outf[n] = 1.f / (1.f + expf(-s));
    } else {
      ushort4 pk;
      pk.x = f2bf(dn * fmaf(dn, a0, rt.x) * w2[0]);
      pk.y = f2bf(dn * fmaf(dn, a1, rt.y) * w2[1]);
      pk.z = f2bf(dn * fmaf(dn, a2, rt.z) * w2[2]);
      pk.w = 0;
      outp[n] = pk;
    }
  }
}

// ---------- launch ----------
extern "C" void kernel_launch(void* const* d_in, const int* in_sizes, int n_in,
                              void* d_out, int out_size, void* d_ws, size_t ws_size,
                              hipStream_t stream) {
  const float* x     = (const float*)d_in[0];
  const int*   ei    = (const int*)d_in[1];
  const float* ew    = (const float*)d_in[2];
  const float* c1_iw = (const float*)d_in[3];
  const float* c1_w  = (const float*)d_in[4];
  const float* c1_rw = (const float*)d_in[5];
  const float* c1_b  = (const float*)d_in[6];
  const float* bn_g  = (const float*)d_in[7];
  const float* bn_b  = (const float*)d_in[8];
  const float* bn_m  = (const float*)d_in[9];
  const float* bn_v  = (const float*)d_in[10];
  const float* c2_iw = (const float*)d_in[11];
  const float* c2_w  = (const float*)d_in[12];
  const float* c2_rw = (const float*)d_in[13];
  const float* c2_b  = (const float*)d_in[14];
  float* out = (float*)d_out;

  char* p = (char*)d_ws;
  auto take = [&](size_t bytes) -> char* { char* r = p; p += alignup(bytes); return r; };
  int*     cntm   = (int*)take((size_t)NBLK * NBUCK * 4);
  int*     basem  = (int*)take((size_t)(NBLK + 1) * NBUCK * 4);
  int*     btot   = (int*)take((size_t)NBUCK * 4);
  int*     gbase  = (int*)take((size_t)NBUCK * 4);
  int*     csrT   = (int*)take((size_t)NE * 4);
  unsigned char* colb = (unsigned char*)take((size_t)NE);
  int*     csr    = (int*)take((size_t)NE * 4);
  float*   dis    = (float*)take((size_t)NN * 4);
  int*     nst    = (int*)take((size_t)NN * 4);
  int*     ncn    = (int*)take((size_t)NN * 4);
  unsigned short* root1 = (unsigned short*)take((size_t)NN * 48 * 2);
  float*   sbuf   = (float*)take((size_t)NN * 4);
  ushort4* bufA   = (ushort4*)take((size_t)NN * 16 * 8);
  ushort4* bufB   = (ushort4*)take((size_t)NN * 16 * 8);
  float4*  root2  = (float4*)take((size_t)NN * 16);
  ushort4* o2A    = (ushort4*)take((size_t)NN * 8);
  ushort4* o2B    = (ushort4*)take((size_t)NN * 8);

  const int* row = ei;
  const int* col = ei + NE;

  const int gP = (NN * 16 + 255) / 256;
  const int gSB = (NBUCK + SB_Q - 1) / SB_Q;

  k_hist <<<NBLK, 256, 0, stream>>>(col, cntm);
  k_scanb<<<gSB, 256, 0, stream>>>(cntm, basem, btot);
  k_scanq<<<1, 256, 0, stream>>>(btot, gbase);
  k_scat <<<NBLK, 256, 0, stream>>>(row, col, ew, basem, gbase, csrT, colb);
  k_build<<<NBUCK, 256, 0, stream>>>(gbase, btot, csrT, colb, csr, dis, nst, ncn);

  k_init1<<<gP, 256, 0, stream>>>(x, c1_rw, c1_b, dis, root1, sbuf);
  k_prop_first<<<gP, 256, 0, stream>>>(sbuf, root1, bufA, csr, nst, ncn, dis, c1_w, c1_iw);
  k_prop16<true ><<<gP, 256, 0, stream>>>(bufA, root1, bufB, csr, nst, ncn, dis, c1_w,
      nullptr, nullptr, nullptr, nullptr, nullptr, nullptr, nullptr, nullptr, nullptr);
  k_prop16<true ><<<gP, 256, 0, stream>>>(bufB, root1, bufA, csr, nst, ncn, dis, c1_w,
      nullptr, nullptr, nullptr, nullptr, nullptr, nullptr, nullptr, nullptr, nullptr);
  k_prop16<false><<<gP, 256, 0, stream>>>(bufA, root1, nullptr, csr, nst, ncn, dis, nullptr,
      bn_g, bn_b, bn_m, bn_v, c2_iw, c2_rw, c2_b, root2, o2A);

  k_prop1<false><<<gP, 256, 0, stream>>>(o2A, root2, o2B, nullptr, csr, nst, ncn, dis, c2_w);
  k_prop1<false><<<gP, 256, 0, stream>>>(o2B, root2, o2A, nullptr, csr, nst, ncn, dis, c2_w);
  k_prop1<false><<<gP, 256, 0, stream>>>(o2A, root2, o2B, nullptr, csr, nst, ncn, dis, c2_w);
  k_prop1<true ><<<gP, 256, 0, stream>>>(o2B, root2, nullptr, out, csr, nst, ncn, dis, c2_w);
}

// Round 15
// 371.337 us; speedup vs baseline: 1.1939x; 1.0324x over previous
//
#include <hip/hip_runtime.h>
#include <math.h>

#define NN 100000
#define NE 3200000
#define NBUCK 782   // buckets of 128 cols
#define EPB 4096    // edges per partition block
#define NBLK 782    // ceil(NE/EPB)
#define SB_Q 16     // buckets per k_scanb block
#define SCAP 4608   // k_build LDS stage capacity (mean 4092, +8 sigma)
#define PCAP 1536   // k_prop16 CSR LDS stage (mean 512/block, 45 sigma)
#define BN_EPS 1e-5f

static inline size_t alignup(size_t v) { return (v + 255) & ~size_t(255); }

__device__ inline unsigned short f2bf(float x) {  // round-to-nearest bf16
  unsigned u = __float_as_uint(x);
  u += 0x7FFF + ((u >> 16) & 1);
  return (unsigned short)(u >> 16);
}
__device__ inline float bf2f(unsigned short h) {
  return __uint_as_float((unsigned)h << 16);
}
// edge entry: bits[16:0]=row, bits[31:17]=top 15 bits of fp32 weight (RN)
__device__ inline float edgew(int e) {
  return __uint_as_float((unsigned)e & 0xFFFE0000u);
}
__device__ inline int packent(int r, float w) {  // row | RN15(w)
  unsigned u = __float_as_uint(w);
  u += 0xFFFFu + ((u >> 17) & 1);
  return r | (int)(u & 0xFFFE0000u);
}

// ---------- A: per-block bucket histogram ----------
__global__ void k_hist(const int* __restrict__ col, int* __restrict__ cntm) {
  __shared__ int cnt[NBUCK];
  for (int i = threadIdx.x; i < NBUCK; i += 256) cnt[i] = 0;
  __syncthreads();
  int e0 = blockIdx.x * EPB;
  int nE = min(EPB, NE - e0);
  for (int i = threadIdx.x; i < nE; i += 256) atomicAdd(&cnt[col[e0 + i] >> 7], 1);
  __syncthreads();
  int* dst = cntm + (size_t)blockIdx.x * NBUCK;
  for (int i = threadIdx.x; i < NBUCK; i += 256) dst[i] = cnt[i];
}

// ---------- B: per-bucket exclusive scan over blocks (+ total row NBLK) ----------
__global__ void k_scanb(const int* __restrict__ cntm, int* __restrict__ basem,
                        int* __restrict__ btot) {
  __shared__ int s[NBLK][SB_Q + 1];
  int q0 = blockIdx.x * SB_Q;
  int nq = min(SB_Q, NBUCK - q0);
  int t = threadIdx.x;
  for (int idx = t; idx < NBLK * SB_Q; idx += 256) {
    int i = idx >> 4, j = idx & 15;
    s[i][j] = (j < nq) ? cntm[(size_t)i * NBUCK + q0 + j] : 0;
  }
  __syncthreads();
  int wave = t >> 6, lane = t & 63;
  for (int j = wave; j < SB_Q; j += 4) {
    int carry = 0;
    for (int c = 0; c < (NBLK + 63) / 64; ++c) {
      int i = c * 64 + lane;
      int v = (i < NBLK) ? s[i][j] : 0;
      int x = v;
      #pragma unroll
      for (int d = 1; d < 64; d <<= 1) {
        int tt = __shfl_up(x, d, 64);
        if (lane >= d) x += tt;
      }
      if (i < NBLK) s[i][j] = x - v + carry;
      carry += __shfl(x, 63, 64);
    }
    if (lane == 0 && j < nq) {
      btot[q0 + j] = carry;
      basem[(size_t)NBLK * NBUCK + q0 + j] = carry;  // total row
    }
  }
  __syncthreads();
  for (int idx = t; idx < NBLK * SB_Q; idx += 256) {
    int i = idx >> 4, j = idx & 15;
    if (j < nq) basem[(size_t)i * NBUCK + q0 + j] = s[i][j];
  }
}

// ---------- C: exclusive scan of bucket totals ----------
__global__ void k_scanq(const int* __restrict__ btot, int* __restrict__ gbase) {
  __shared__ int s[NBUCK];
  __shared__ int c[256];
  const int NCH = (NBUCK + 3) / 4;
  int t = threadIdx.x;
  for (int i = t; i < NBUCK; i += 256) s[i] = btot[i];
  __syncthreads();
  if (t < NCH) {
    int b0 = 4 * t, sum = 0;
    #pragma unroll
    for (int j = 0; j < 4; ++j) if (b0 + j < NBUCK) sum += s[b0 + j];
    c[t] = sum;
  }
  __syncthreads();
  for (int d = 1; d < NCH; d <<= 1) {
    int v = (t < NCH && t >= d) ? c[t - d] : 0;
    __syncthreads();
    if (t < NCH) c[t] += v;
    __syncthreads();
  }
  if (t < NCH) {
    int b0 = 4 * t;
    int run = (t > 0) ? c[t - 1] : 0;
    #pragma unroll
    for (int j = 0; j < 4; ++j)
      if (b0 + j < NBUCK) { int v = s[b0 + j]; s[b0 + j] = run; run += v; }
  }
  __syncthreads();
  for (int i = t; i < NBUCK; i += 256) gbase[i] = s[i];
}

// ---------- D: scatter -> final 4B entries + 1B bucket-local cols ----------
__global__ void k_scat(const int* __restrict__ row, const int* __restrict__ col,
                       const float* __restrict__ ew, const int* __restrict__ basem,
                       const int* __restrict__ gbase, int* __restrict__ csrT,
                       unsigned char* __restrict__ colb) {
  __shared__ int segB[NBUCK];
  __shared__ int cnt[NBUCK];
  __shared__ int csc[256];
  __shared__ int stage[EPB];
  __shared__ unsigned char stc[EPB];
  __shared__ unsigned short qarr[EPB];
  int b = blockIdx.x, t = threadIdx.x;
  const int* rowA = basem + (size_t)b * NBUCK;
  const int* rowB = basem + (size_t)(b + 1) * NBUCK;
  for (int i = t; i < NBUCK; i += 256) {
    int a = rowA[i];
    segB[i] = gbase[i] + a;
    cnt[i] = rowB[i] - a;
  }
  __syncthreads();
  const int NCH = (NBUCK + 3) / 4;
  int q4 = 4 * t;
  if (t < NCH) {
    int sum = 0;
    #pragma unroll
    for (int j = 0; j < 4; ++j) if (q4 + j < NBUCK) sum += cnt[q4 + j];
    csc[t] = sum;
  }
  __syncthreads();
  for (int d = 1; d < NCH; d <<= 1) {
    int v = (t < NCH && t >= d) ? csc[t - d] : 0;
    __syncthreads();
    if (t < NCH) csc[t] += v;
    __syncthreads();
  }
  if (t < NCH) {
    int run = (t > 0) ? csc[t - 1] : 0;
    #pragma unroll
    for (int j = 0; j < 4; ++j)
      if (q4 + j < NBUCK) {
        int v = cnt[q4 + j];
        segB[q4 + j] -= run;
        cnt[q4 + j] = run;
        run += v;
      }
  }
  __syncthreads();
  int e0 = b * EPB;
  int nE = min(EPB, NE - e0);
  for (int i = t; i < nE; i += 256) {
    int e = e0 + i;
    int cc = col[e], q = cc >> 7;
    int p = atomicAdd(&cnt[q], 1);
    stage[p] = packent(row[e], ew[e]);
    stc[p] = (unsigned char)(cc & 127);
    qarr[p] = (unsigned short)q;
  }
  __syncthreads();
  for (int p = t; p < nE; p += 256) {
    int q = qarr[p];
    int dst = segB[q] + p;
    csrT[dst] = stage[p];
    colb[dst] = stc[p];
  }
}

// ---------- E: per-bucket counting sort (4B entries + col bytes) ----------
__global__ void k_build(const int* __restrict__ gbase, const int* __restrict__ btot,
                        const int* __restrict__ csrT, const unsigned char* __restrict__ colb,
                        int* __restrict__ csr, float* __restrict__ dis,
                        int* __restrict__ nstart, int* __restrict__ ncnt) {
  __shared__ int stage[SCAP];
  __shared__ unsigned char scol[SCAP];
  __shared__ int cnt[128];
  __shared__ float degw[128];
  __shared__ int off[129];
  int b = blockIdx.x;
  int gb0 = gbase[b];
  int nb = btot[b];
  const int* ct = csrT + gb0;
  const unsigned char* cbv = colb + gb0;
  for (int i = threadIdx.x; i < 128; i += 256) { cnt[i] = 0; degw[i] = 0.f; }
  __syncthreads();
  for (int i = threadIdx.x; i < nb; i += 256) {
    int v = ct[i];
    unsigned char c = cbv[i];
    if (i < SCAP) { stage[i] = v; scol[i] = c; }
    atomicAdd(&cnt[c], 1);
    atomicAdd(&degw[c], edgew(v));
  }
  __syncthreads();
  if (threadIdx.x == 0) {
    int s = 0;
    for (int c = 0; c < 128; ++c) { off[c] = s; s += cnt[c]; }
    off[128] = s;
  }
  __syncthreads();
  for (int c = threadIdx.x; c < 128; c += 256) {
    int n = b * 128 + c;
    if (n < NN) {
      nstart[n] = gb0 + off[c];
      ncnt[n] = cnt[c];
      float d = degw[c];
      dis[n] = (d > 0.f) ? rsqrtf(fmaxf(d, 1e-12f)) : 0.f;
    }
  }
  __syncthreads();
  for (int i = threadIdx.x; i < 128; i += 256) cnt[i] = 0;
  __syncthreads();
  int* cb = csr + gb0;
  for (int i = threadIdx.x; i < nb; i += 256) {
    int v; unsigned char c;
    if (i < SCAP) { v = stage[i]; c = scol[i]; }
    else { v = ct[i]; c = cbv[i]; }
    int pos = off[c] + atomicAdd(&cnt[c], 1);
    cb[pos] = v;
  }
}

// ---------- conv1 ----------
__global__ void k_init1(const float* __restrict__ x, const float* __restrict__ rw,
                        const float* __restrict__ bias, const float* __restrict__ dis,
                        unsigned short* __restrict__ root1, float* __restrict__ s) {
  int idx = blockIdx.x * 256 + threadIdx.x;  // n*16 + f
  if (idx >= NN * 16) return;
  int n = idx >> 4, f = idx & 15;
  float xv = x[n];
  if (f == 0) s[n] = dis[n] * xv;
  root1[n * 48 + f]      = f2bf(xv * rw[f]      + bias[f]);
  root1[n * 48 + 16 + f] = f2bf(xv * rw[16 + f] + bias[16 + f]);
  root1[n * 48 + 32 + f] = f2bf(xv * rw[32 + f] + bias[32 + f]);
}

// Pass 1 exploits rank-1 input: gather is a SCALAR sum g = sum_e w_e*dis_r*x_r.
__global__ void k_prop_first(const float* __restrict__ s,
                             const unsigned short* __restrict__ root,
                             ushort4* __restrict__ outp, const int* __restrict__ csr,
                             const int* __restrict__ nstart, const int* __restrict__ ncnt,
                             const float* __restrict__ dis, const float* __restrict__ w,
                             const float* __restrict__ iw) {
  __shared__ float ws[768];
  for (int i = threadIdx.x; i < 768; i += 256) ws[i] = w[i];
  __syncthreads();
  int f = threadIdx.x & 15;
  int n = (blockIdx.x * 256 + threadIdx.x) >> 4;
  if (n >= NN) return;
  int e0 = nstart[n], cnt = ncnt[n];
  float g = 0.f;
  for (int i = f; i < cnt; i += 16) {
    int e = csr[e0 + i];
    g = fmaf(edgew(e), s[e & 0x1FFFF], g);
  }
  #pragma unroll
  for (int d = 8; d; d >>= 1) g += __shfl_xor(g, d, 16);
  float dn = dis[n];
  float dg = dn * g;
  float a0 = fmaxf(fmaf(dg, iw[f],      bf2f(root[n * 48 + f])),      0.f);
  float a1 = fmaxf(fmaf(dg, iw[16 + f], bf2f(root[n * 48 + 16 + f])), 0.f);
  float a2 = fmaxf(fmaf(dg, iw[32 + f], bf2f(root[n * 48 + 32 + f])), 0.f);
  float n0 = 0.f, n1 = 0.f, n2 = 0.f;
  #pragma unroll
  for (int f2 = 0; f2 < 16; ++f2) {
    float b0 = __shfl(a0, f2, 16);
    float b1 = __shfl(a1, f2, 16);
    float b2v = __shfl(a2, f2, 16);
    n0 = fmaf(b0, ws[f2 * 16 + f], n0);
    n1 = fmaf(b1, ws[256 + f2 * 16 + f], n1);
    n2 = fmaf(b2v, ws[512 + f2 * 16 + f], n2);
  }
  ushort4 pk;
  pk.x = f2bf(dn * n0); pk.y = f2bf(dn * n1); pk.z = f2bf(dn * n2); pk.w = 0;
  outp[(size_t)n * 16 + f] = pk;
}

// Edge-loop bodies, parameterized on the CSR fetch expression.
#define P16_LOOPS(FETCH)                                                      \
  {                                                                           \
    int i = 0;                                                                \
    for (; i + 16 <= cnt; i += 16) {                                          \
      int e[16];                                                              \
      ushort4 v[16];                                                          \
      _Pragma("unroll")                                                       \
      for (int j = 0; j < 16; ++j) e[j] = FETCH(i + j);                       \
      _Pragma("unroll")                                                       \
      for (int j = 0; j < 16; ++j) v[j] = in[(size_t)(e[j] & 0x1FFFF) * 16 + f]; \
      _Pragma("unroll")                                                       \
      for (int j = 0; j < 16; ++j) {                                          \
        float we = edgew(e[j]);                                               \
        a0 = fmaf(we, bf2f(v[j].x), a0);                                      \
        a1 = fmaf(we, bf2f(v[j].y), a1);                                      \
        a2 = fmaf(we, bf2f(v[j].z), a2);                                      \
      }                                                                       \
    }                                                                         \
    for (; i + 4 <= cnt; i += 4) {                                            \
      int e[4];                                                               \
      ushort4 v[4];                                                           \
      _Pragma("unroll")                                                       \
      for (int j = 0; j < 4; ++j) e[j] = FETCH(i + j);                        \
      _Pragma("unroll")                                                       \
      for (int j = 0; j < 4; ++j) v[j] = in[(size_t)(e[j] & 0x1FFFF) * 16 + f]; \
      _Pragma("unroll")                                                       \
      for (int j = 0; j < 4; ++j) {                                           \
        float we = edgew(e[j]);                                               \
        a0 = fmaf(we, bf2f(v[j].x), a0);                                      \
        a1 = fmaf(we, bf2f(v[j].y), a1);                                      \
        a2 = fmaf(we, bf2f(v[j].z), a2);                                      \
      }                                                                       \
    }                                                                         \
    for (; i < cnt; ++i) {                                                    \
      int e = FETCH(i);                                                       \
      float we = edgew(e);                                                    \
      ushort4 v = in[(size_t)(e & 0x1FFFF) * 16 + f];                         \
      a0 = fmaf(we, bf2f(v.x), a0);                                           \
      a1 = fmaf(we, bf2f(v.y), a1);                                           \
      a2 = fmaf(we, bf2f(v.z), a2);                                           \
    }                                                                         \
  }

#define F_LDS(k) scsr[lo + (k)]
#define F_GLB(k) csr[e0 + (k)]

// 16 lanes per dest node. Block's 16 nodes have CONTIGUOUS CSR segments
// (within-bucket scan; 128%16==0 so blocks never straddle buckets) -> stage
// the whole segment in LDS once (coalesced), edge loop reads indices from LDS.
template <bool APPLY_W>
__global__ __launch_bounds__(256, 6)
void k_prop16(const ushort4* __restrict__ in,
              const unsigned short* __restrict__ root,
              ushort4* __restrict__ outp, const int* __restrict__ csr,
              const int* __restrict__ nstart, const int* __restrict__ ncnt,
              const float* __restrict__ dis, const float* __restrict__ w,
              const float* __restrict__ bng, const float* __restrict__ bnb,
              const float* __restrict__ bnm, const float* __restrict__ bnv,
              const float* __restrict__ iw2, const float* __restrict__ rw2,
              const float* __restrict__ b2,
              float4* __restrict__ root2, ushort4* __restrict__ o2) {
  __shared__ float ws[768];
  __shared__ int scsr[PCAP];
  int nb0 = blockIdx.x * 16;                 // NN%16==0: all blocks full
  int segA = nstart[nb0];
  int segZ = nstart[nb0 + 15] + ncnt[nb0 + 15];
  int segLen = segZ - segA;
  if (APPLY_W) {
    for (int i = threadIdx.x; i < 768; i += 256) ws[i] = w[i];
  }
  int nstage = min(segLen, PCAP);
  for (int i = threadIdx.x; i < nstage; i += 256) scsr[i] = csr[segA + i];
  __syncthreads();
  int f = threadIdx.x & 15;
  int n = nb0 + (threadIdx.x >> 4);
  int e0 = nstart[n], cnt = ncnt[n];
  float a0 = 0.f, a1 = 0.f, a2 = 0.f;
  if (segLen <= PCAP) {
    int lo = e0 - segA;
    P16_LOOPS(F_LDS)
  } else {
    P16_LOOPS(F_GLB)
  }
  float dn = dis[n];
  a0 = fmaxf(fmaf(dn, a0, bf2f(root[n * 48 + f])),      0.f);
  a1 = fmaxf(fmaf(dn, a1, bf2f(root[n * 48 + 16 + f])), 0.f);
  a2 = fmaxf(fmaf(dn, a2, bf2f(root[n * 48 + 32 + f])), 0.f);
  if (APPLY_W) {
    float n0 = 0.f, n1 = 0.f, n2 = 0.f;
    #pragma unroll
    for (int f2 = 0; f2 < 16; ++f2) {
      float b0 = __shfl(a0, f2, 16);
      float b1 = __shfl(a1, f2, 16);
      float b2v = __shfl(a2, f2, 16);
      n0 = fmaf(b0, ws[f2 * 16 + f], n0);
      n1 = fmaf(b1, ws[256 + f2 * 16 + f], n1);
      n2 = fmaf(b2v, ws[512 + f2 * 16 + f], n2);
    }
    ushort4 pk;
    pk.x = f2bf(dn * n0); pk.y = f2bf(dn * n1); pk.z = f2bf(dn * n2); pk.w = 0;
    outp[(size_t)n * 16 + f] = pk;
  } else {
    float mean = (a0 + a1 + a2) * (1.f / 3.f);
    float hv = fmaxf((mean - bnm[f]) * rsqrtf(bnv[f] + BN_EPS) * bng[f] + bnb[f], 0.f);
    float d0 = hv * iw2[f],      r0 = hv * rw2[f];
    float d1 = hv * iw2[16 + f], r1 = hv * rw2[16 + f];
    float d2 = hv * iw2[32 + f], r2 = hv * rw2[32 + f];
    #pragma unroll
    for (int d = 8; d; d >>= 1) {
      d0 += __shfl_xor(d0, d, 16); r0 += __shfl_xor(r0, d, 16);
      d1 += __shfl_xor(d1, d, 16); r1 += __shfl_xor(r1, d, 16);
      d2 += __shfl_xor(d2, d, 16); r2 += __shfl_xor(r2, d, 16);
    }
    if (f == 0) {
      float4 rt;
      rt.x = r0 + b2[0]; rt.y = r1 + b2[1]; rt.z = r2 + b2[2]; rt.w = 0.f;
      root2[n] = rt;
      ushort4 pk;
      pk.x = f2bf(dn * d0); pk.y = f2bf(dn * d1); pk.z = f2bf(dn * d2); pk.w = 0;
      o2[n] = pk;
    }
  }
}

// ---------- conv2: 16 lanes split edges; state bf16 ushort4 ----------
template <bool LAST>
__global__ void k_prop1(const ushort4* __restrict__ in, const float4* __restrict__ root,
                        ushort4* __restrict__ outp, float* __restrict__ outf,
                        const int* __restrict__ csr,
                        const int* __restrict__ nstart, const int* __restrict__ ncnt,
                        const float* __restrict__ dis, const float* __restrict__ w2) {
  int lane = threadIdx.x & 15;
  int n = (blockIdx.x * 256 + threadIdx.x) >> 4;
  if (n >= NN) return;
  int e0 = nstart[n], cnt = ncnt[n];
  float a0 = 0.f, a1 = 0.f, a2 = 0.f;
  for (int i = lane; i < cnt; i += 16) {
    int e = csr[e0 + i];
    float we = edgew(e);
    ushort4 src = in[e & 0x1FFFF];
    a0 = fmaf(we, bf2f(src.x), a0);
    a1 = fmaf(we, bf2f(src.y), a1);
    a2 = fmaf(we, bf2f(src.z), a2);
  }
  #pragma unroll
  for (int d = 8; d; d >>= 1) {
    a0 += __shfl_xor(a0, d, 16);
    a1 += __shfl_xor(a1, d, 16);
    a2 += __shfl_xor(a2, d, 16);
  }
  if (lane == 0) {
    float dn = dis[n];
    float4 rt = root[n];
    if (LAST) {
      float s = fmaf(dn, a0, rt.x) + fmaf(dn, a1, rt.y) + fmaf(dn, a2, rt.z);
      s *= (1.f / 3.f);
      outf[n] = 1.f / (1.f + expf(-s));
    } else {
      ushort4 pk;
      pk.x = f2bf(dn * fmaf(dn, a0, rt.x) * w2[0]);
      pk.y = f2bf(dn * fmaf(dn, a1, rt.y) * w2[1]);
      pk.z = f2bf(dn * fmaf(dn, a2, rt.z) * w2[2]);
      pk.w = 0;
      outp[n] = pk;
    }
  }
}

// ---------- launch ----------
extern "C" void kernel_launch(void* const* d_in, const int* in_sizes, int n_in,
                              void* d_out, int out_size, void* d_ws, size_t ws_size,
                              hipStream_t stream) {
  const float* x     = (const float*)d_in[0];
  const int*   ei    = (const int*)d_in[1];
  const float* ew    = (const float*)d_in[2];
  const float* c1_iw = (const float*)d_in[3];
  const float* c1_w  = (const float*)d_in[4];
  const float* c1_rw = (const float*)d_in[5];
  const float* c1_b  = (const float*)d_in[6];
  const float* bn_g  = (const float*)d_in[7];
  const float* bn_b  = (const float*)d_in[8];
  const float* bn_m  = (const float*)d_in[9];
  const float* bn_v  = (const float*)d_in[10];
  const float* c2_iw = (const float*)d_in[11];
  const float* c2_w  = (const float*)d_in[12];
  const float* c2_rw = (const float*)d_in[13];
  const float* c2_b  = (const float*)d_in[14];
  float* out = (float*)d_out;

  char* p = (char*)d_ws;
  auto take = [&](size_t bytes) -> char* { char* r = p; p += alignup(bytes); return r; };
  int*     cntm   = (int*)take((size_t)NBLK * NBUCK * 4);
  int*     basem  = (int*)take((size_t)(NBLK + 1) * NBUCK * 4);
  int*     btot   = (int*)take((size_t)NBUCK * 4);
  int*     gbase  = (int*)take((size_t)NBUCK * 4);
  int*     csrT   = (int*)take((size_t)NE * 4);
  unsigned char* colb = (unsigned char*)take((size_t)NE);
  int*     csr    = (int*)take((size_t)NE * 4);
  float*   dis    = (float*)take((size_t)NN * 4);
  int*     nst    = (int*)take((size_t)NN * 4);
  int*     ncn    = (int*)take((size_t)NN * 4);
  unsigned short* root1 = (unsigned short*)take((size_t)NN * 48 * 2);
  float*   sbuf   = (float*)take((size_t)NN * 4);
  ushort4* bufA   = (ushort4*)take((size_t)NN * 16 * 8);
  ushort4* bufB   = (ushort4*)take((size_t)NN * 16 * 8);
  float4*  root2  = (float4*)take((size_t)NN * 16);
  ushort4* o2A    = (ushort4*)take((size_t)NN * 8);
  ushort4* o2B    = (ushort4*)take((size_t)NN * 8);

  const int* row = ei;
  const int* col = ei + NE;

  const int gP = (NN * 16 + 255) / 256;
  const int gSB = (NBUCK + SB_Q - 1) / SB_Q;

  k_hist <<<NBLK, 256, 0, stream>>>(col, cntm);
  k_scanb<<<gSB, 256, 0, stream>>>(cntm, basem, btot);
  k_scanq<<<1, 256, 0, stream>>>(btot, gbase);
  k_scat <<<NBLK, 256, 0, stream>>>(row, col, ew, basem, gbase, csrT, colb);
  k_build<<<NBUCK, 256, 0, stream>>>(gbase, btot, csrT, colb, csr, dis, nst, ncn);

  k_init1<<<gP, 256, 0, stream>>>(x, c1_rw, c1_b, dis, root1, sbuf);
  k_prop_first<<<gP, 256, 0, stream>>>(sbuf, root1, bufA, csr, nst, ncn, dis, c1_w, c1_iw);
  k_prop16<true ><<<gP, 256, 0, stream>>>(bufA, root1, bufB, csr, nst, ncn, dis, c1_w,
      nullptr, nullptr, nullptr, nullptr, nullptr, nullptr, nullptr, nullptr, nullptr);
  k_prop16<true ><<<gP, 256, 0, stream>>>(bufB, root1, bufA, csr, nst, ncn, dis, c1_w,
      nullptr, nullptr, nullptr, nullptr, nullptr, nullptr, nullptr, nullptr, nullptr);
  k_prop16<false><<<gP, 256, 0, stream>>>(bufA, root1, nullptr, csr, nst, ncn, dis, nullptr,
      bn_g, bn_b, bn_m, bn_v, c2_iw, c2_rw, c2_b, root2, o2A);

  k_prop1<false><<<gP, 256, 0, stream>>>(o2A, root2, o2B, nullptr, csr, nst, ncn, dis, c2_w);
  k_prop1<false><<<gP, 256, 0, stream>>>(o2B, root2, o2A, nullptr, csr, nst, ncn, dis, c2_w);
  k_prop1<false><<<gP, 256, 0, stream>>>(o2A, root2, o2B, nullptr, csr, nst, ncn, dis, c2_w);
  k_prop1<true ><<<gP, 256, 0, stream>>>(o2B, root2, nullptr, out, csr, nst, ncn, dis, c2_w);
}